// Round 8
// baseline (174.612 us; speedup 1.0000x reference)
//
#include <hip/hip_runtime.h>
#include <hip/hip_bf16.h>
#include <math.h>

#define BB 8
#define CC 384
#define NT 1024
#define NHEAD 8
#define HD 48
#define HIDDEN 192
#define THREEC 1152

typedef short short8 __attribute__((ext_vector_type(8)));
typedef short short4v __attribute__((ext_vector_type(4)));
typedef float f32x4 __attribute__((ext_vector_type(4)));
typedef unsigned int uint2v __attribute__((ext_vector_type(2)));
typedef unsigned int uint4v __attribute__((ext_vector_type(4)));

static __device__ __forceinline__ short bf16bits(float v) {
  __hip_bfloat16 h = __float2bfloat16(v);
  return *(short*)&h;
}
// pack two fp32 -> two bf16 (round-half-up) in 3 ops via v_perm_b32
static __device__ __forceinline__ unsigned pk2(float a, float b) {
  return __builtin_amdgcn_perm(__float_as_uint(b) + 0x8000u,
                               __float_as_uint(a) + 0x8000u, 0x07060302u);
}
// async global->LDS DMA, 16B per lane; LDS dest = base + lane*16
static __device__ __forceinline__ void lds_dma16(const void* g, void* l) {
  __builtin_amdgcn_global_load_lds((const __attribute__((address_space(1))) unsigned*)g,
                                   (__attribute__((address_space(3))) unsigned*)l, 16, 0, 0);
}
// gfx950 cross-lane: A'=[A0,B0,A2,B2], B'=[A1,B1,A3,B3] (16-lane rows)
static __device__ __forceinline__ void pl16swap(unsigned& a, unsigned& b) {
  asm("v_permlane16_swap_b32 %0, %1" : "+v"(a), "+v"(b));
}

// ---------------- fused prep: x/wq/wp transposes + bias table, one launch ----------------
// blocks [0,3072): x transpose; [3072,3504): qkv_w; [3504,3648): proj_w; [3648,3773): bias
__global__ __launch_bounds__(256) void k_prep(
    const float* __restrict__ x, const float* __restrict__ qkv_w,
    const float* __restrict__ proj_w,
    const float* __restrict__ w1, const float* __restrict__ b1,
    const float* __restrict__ w2, const float* __restrict__ b2,
    __hip_bfloat16* __restrict__ xt, __hip_bfloat16* __restrict__ wtq,
    __hip_bfloat16* __restrict__ wtp, float* __restrict__ tab) {
  const int bid = blockIdx.x;
  const int tid = threadIdx.x;
  if (bid >= 3648) {  // ---- bias table ----
    int g = (bid - 3648) * 256 + tid;
    int p = g >> 3, jc = g & 7;
    if (p >= 63 * 63) return;
    float rh = (float)(p / 63 - 31) * (1.0f / 31.0f);
    float rw = (float)(p % 63 - 31) * (1.0f / 31.0f);
    float acc[8] = {0.f, 0.f, 0.f, 0.f, 0.f, 0.f, 0.f, 0.f};
    const int j0 = jc * 24;
#pragma unroll 4
    for (int j = j0; j < j0 + 24; j++) {
      float pre = fmaf(rh, w1[j], fmaf(rw, w1[HIDDEN + j], b1[j]));
      float gl = 0.5f * pre * (1.0f + erff(pre * 0.70710678118654752f));
#pragma unroll
      for (int h = 0; h < 8; h++) acc[h] = fmaf(gl, w2[j * 8 + h], acc[h]);
    }
#pragma unroll
    for (int msk = 1; msk <= 4; msk <<= 1)
#pragma unroll
      for (int h = 0; h < 8; h++) acc[h] += __shfl_xor(acc[h], msk);
    if (jc == 0) {
#pragma unroll
      for (int h = 0; h < 8; h++)
        tab[h * 3969 + p] = (acc[h] + b2[h]) * 1.4426950408889634f;
    }
    return;
  }
  // ---- transposes ----
  const float* src;
  __hip_bfloat16* dst;
  int R, C, r0, c0;
  if (bid < 3072) {
    int zi = bid / 384, rem = bid % 384;
    R = 384; C = 1024;
    r0 = (rem / 32) * 32; c0 = (rem % 32) * 32;
    src = x + (size_t)zi * R * C;
    dst = xt + (size_t)zi * R * C;
  } else if (bid < 3504) {
    int i = bid - 3072;
    R = 384; C = 1152;
    r0 = (i / 36) * 32; c0 = (i % 36) * 32;
    src = qkv_w; dst = wtq;
  } else {
    int i = bid - 3504;
    R = 384; C = 384;
    r0 = (i / 12) * 32; c0 = (i % 12) * 32;
    src = proj_w; dst = wtp;
  }
  __shared__ float t[32][33];
#pragma unroll
  for (int e = 0; e < 4; e++) {
    int i = tid + e * 256;
    int r = i >> 5, c = i & 31;
    t[r][c] = src[(size_t)(r0 + r) * C + c0 + c];
  }
  __syncthreads();
#pragma unroll
  for (int e = 0; e < 4; e++) {
    int i = tid + e * 256;
    int c = i >> 5, r = i & 31;
    dst[(size_t)(c0 + c) * R + r0 + r] = __float2bfloat16(t[r][c]);
  }
}

// ---------------- QKV GEMM (bf16 MFMA), 64x128 tile, 8 waves ----------------
__global__ __launch_bounds__(512) void k_qkv_mfma(
    const __hip_bfloat16* __restrict__ xt,   // [8192][384]
    const __hip_bfloat16* __restrict__ wtq,  // [1152][384]
    const float* __restrict__ qkv_b,
    __hip_bfloat16* __restrict__ Qb,  // [64][1024][64], d-pad zeroed here
    __hip_bfloat16* __restrict__ Kb,  // [64][1024][64], d-pad zeroed here
    __hip_bfloat16* __restrict__ Vt)  // [64][48][1024]
{
  __shared__ __align__(16) char smem[34816];  // staging 24.6KB; epilogue Vf 128x68 f32
  short* As = (short*)smem;           // 64x64 shorts (x tokens), swizzled
  short* Bs = (short*)(smem + 8192);  // 128x64 shorts (w rows), swizzled
  float* Vf = (float*)smem;           // 128x68 f32 reuse
  const int n0 = blockIdx.x * 128;  // out-channel tile (9 tiles; each wholly Q/K/V)
  const int m0 = blockIdx.y * 64;   // token tile
  const int tid = threadIdx.x;
  const int wv = tid >> 6, lane = tid & 63, quad = lane >> 4, lq = lane & 15;
  const int wc = wv >> 2, wm = wv & 3;  // channel-half, token-group
  const int lrow = lane >> 3;
  const int gsw = ((lane & 7) ^ lrow) * 8;
  const int sw0 = (quad ^ (lq & 7)) * 8;
  const int sw1 = sw0 ^ 32;
  f32x4 acc[4];
#pragma unroll
  for (int nt = 0; nt < 4; nt++) acc[nt] = (f32x4){0.f, 0.f, 0.f, 0.f};
  for (int kk = 0; kk < CC; kk += 64) {
    __syncthreads();
    for (int c = wv; c < 24; c += 8) {
      if (c < 8)
        lds_dma16((const short*)xt + (size_t)(m0 + c * 8 + lrow) * 384 + kk + gsw,
                  smem + c * 1024);
      else
        lds_dma16((const short*)wtq + (size_t)(n0 + (c - 8) * 8 + lrow) * 384 + kk + gsw,
                  smem + 8192 + (c - 8) * 1024);
    }
    __syncthreads();
    short8 a0 = *(const short8*)(As + (wm * 16 + lq) * 64 + sw0);
    short8 a1 = *(const short8*)(As + (wm * 16 + lq) * 64 + sw1);
    __builtin_amdgcn_s_setprio(1);
#pragma unroll
    for (int nt = 0; nt < 4; nt++) {
      acc[nt] = __builtin_amdgcn_mfma_f32_16x16x32_bf16(
          a0, *(const short8*)(Bs + (wc * 64 + nt * 16 + lq) * 64 + sw0), acc[nt], 0, 0, 0);
      acc[nt] = __builtin_amdgcn_mfma_f32_16x16x32_bf16(
          a1, *(const short8*)(Bs + (wc * 64 + nt * 16 + lq) * 64 + sw1), acc[nt], 0, 0, 0);
    }
    __builtin_amdgcn_s_setprio(0);
  }
  __syncthreads();
  const float qscale = 0.14433756729740643f * 1.4426950408889634f;  // 48^-.5 * log2e
  const float sc = (n0 < 384) ? qscale : 1.0f;
#pragma unroll
  for (int nt = 0; nt < 4; nt++) {
    float bias = qkv_b[n0 + wc * 64 + nt * 16 + lq];
#pragma unroll
    for (int r = 0; r < 4; r++)
      Vf[(wc * 64 + nt * 16 + lq) * 68 + wm * 16 + quad * 4 + r] = (acc[nt][r] + bias) * sc;
  }
  __syncthreads();
  if (n0 >= 768) {
    // ---- V: transposed write [bh][d][n]; 128 ch x 4 token-groups, 32B/thread ----
    int ch = tid & 127, grp = tid >> 7;
    int cg = n0 - 768 + ch;
    int head = cg / 48, d = cg - head * 48;
    int b = m0 >> 10;
    int n = (m0 & 1023) + grp * 16;
    const float* src = Vf + ch * 68 + grp * 16;
    short o16[16];
#pragma unroll
    for (int k = 0; k < 16; k++) o16[k] = bf16bits(src[k]);
    short* dst = (short*)Vt + ((size_t)(b * 8 + head) * 48 + d) * 1024 + n;
    *(short8*)dst = *(short8*)o16;
    *(short8*)(dst + 8) = *(short8*)(o16 + 8);
  } else {
    // ---- Q or K: row-major [bh][n][d]; 8 segs x 16 ch, 32B/thread + d-pad zeros ----
    const int which = n0 >= 384;
    short* Out = which ? (short*)Kb : (short*)Qb;
    int n_l = tid & 63, seg = tid >> 6;  // seg 0..7
    int rr0 = (n0 - which * 384) + seg * 16;  // 16-aligned; 48=3*16 -> no head split
    int head = rr0 / 48, d0 = rr0 - head * 48;
    int b = m0 >> 10;
    int n_g = (m0 & 1023) + n_l;
    const float* src = Vf + (seg * 16) * 68 + n_l;
    short o16[16];
#pragma unroll
    for (int k = 0; k < 16; k++) o16[k] = bf16bits(src[k * 68]);
    short* dst = Out + (((size_t)(b * 8 + head) << 10) + n_g) * 64 + d0;
    *(short8*)dst = *(short8*)o16;
    *(short8*)(dst + 8) = *(short8*)(o16 + 8);
    if (d0 == 0) {
      short8 z = (short8){0, 0, 0, 0, 0, 0, 0, 0};
      *(short8*)(dst + 48) = z;
      *(short8*)(dst + 56) = z;
    }
  }
}

// ---------------- fused flash attention (R14: QBLK=128 + 2-way key-split) ----------------
// Additive no-max softmax => key range split across blockIdx.z (8 tiles each);
// partials (O,L) written from registers, summed by k_comb. K/V/tab stay DMA->LDS
// (R6-proven staging). 1024 blocks -> 4 blocks/CU x 8 waves = 2x occupancy.
#define K0_OFF 0       // K dbuf: 2 x 8192
#define V0_OFF 16384   // V dbuf: 2 x 6144
#define TR_OFF 28672   // tab strips: 2 x 2048
#define SMEM_SZ 32768
__global__ __launch_bounds__(512, 4) void k_flash(
    const __hip_bfloat16* __restrict__ Qb, const __hip_bfloat16* __restrict__ Kb,
    const __hip_bfloat16* __restrict__ Vt, const float* __restrict__ tab,
    float* __restrict__ Opart,  // [2][64][1024][48] f32 (unnormalized)
    float* __restrict__ Lpart)  // [2][64][1024] f32
{
  __shared__ __align__(16) char smem[SMEM_SZ];

  const int tid = threadIdx.x;
  const int wv = tid >> 6, lane = tid & 63, quad = lane >> 4, lq = lane & 15;
  const int bh = blockIdx.x;
  const int q0 = blockIdx.y * 128;
  const int z = blockIdx.z;      // key-half
  const int kt0 = z * 8;         // first key tile of this half
  const int h = bh & 7;
  const int inr0 = q0 >> 5;

  const int nrow = q0 + wv * 16 + lq;
  const int jnr = nrow & 31;
  // strip for key-tile kt is loaded from global tab row (inr0 + 30 - 2kt)
  const int rloc = (nrow >> 5) - inr0 + 1;  // in {1..4}
  // tab strip dword index for (nt,r): tbase - (nt>=2)*63 - (nt&1)*16 - r
  const int tbase = rloc * 63 + jnr + 31 - 4 * quad;  // max 314 < 512

  short8 qf0, qf1;
  {
    const short* qp = (const short*)Qb + ((size_t)(bh << 10) + nrow) * 64;
    qf0 = *(const short8*)(qp + quad * 8);
    qf1 = *(const short8*)(qp + 32 + quad * 8);
  }
  short8 onesv;
#pragma unroll
  for (int j = 0; j < 8; j++) onesv[j] = (short)0x3F80;  // bf16(1.0)

  f32x4 O[4];  // O[3] = L accumulator
#pragma unroll
  for (int dt = 0; dt < 4; dt++) O[dt] = (f32x4){0.f, 0.f, 0.f, 0.f};

  const short* kgp = (const short*)Kb + ((size_t)(bh << 10)) * 64;
  const short* vgp = (const short*)Vt + (size_t)bh * 48 * 1024;
  const float* tabg = tab + h * 3969;
  const int lrow = lane >> 3;
  const int gsw = ((lane & 7) ^ lrow) * 8;
  const int sw0 = (quad ^ (lq & 7)) * 8;
  const int sw1 = sw0 ^ 32;
  // V-read swizzle carries the permlane key-permutation (quad -> vq)
  const int vq = ((quad & 1) << 1) | (quad >> 1);
  const int swv0 = (vq ^ (lq & 7)) * 8;
  const int swv1 = swv0 ^ 32;

  // prologue: DMA tile kt0 + its tab strip -> buf0
  for (int c = wv; c < 16; c += 8) {
    if (c < 8)
      lds_dma16(kgp + (size_t)(kt0 * 64 + c * 8 + lrow) * 64 + gsw,
                smem + K0_OFF + c * 1024);
    else if (c < 14)
      lds_dma16(vgp + (size_t)((c - 8) * 8 + lrow) * 1024 + kt0 * 64 + gsw,
                smem + V0_OFF + (c - 8) * 1024);
    else if (c == 14)
      lds_dma16(tabg + (inr0 + 30 - 2 * kt0) * 63 + lane * 4, smem + TR_OFF);
    else
      lds_dma16(tabg + (inr0 + 30 - 2 * kt0) * 63 + 256 + lane * 4, smem + TR_OFF + 1024);
  }

  for (int it = 0; it < 8; it++) {
    const int kt = kt0 + it;
    const int m0 = kt * 64;
    const int buf = it & 1;
    __syncthreads();  // drains tile-kt DMA (vmcnt0 + barrier)
    if (it < 7) {     // prefetch tile kt+1 into the other buffer
      const int nbuf = buf ^ 1;
      const int mn = m0 + 64;
      for (int c = wv; c < 16; c += 8) {
        if (c < 8)
          lds_dma16(kgp + (size_t)(mn + c * 8 + lrow) * 64 + gsw,
                    smem + K0_OFF + nbuf * 8192 + c * 1024);
        else if (c < 14)
          lds_dma16(vgp + (size_t)((c - 8) * 8 + lrow) * 1024 + mn + gsw,
                    smem + V0_OFF + nbuf * 6144 + (c - 8) * 1024);
        else if (c == 14)
          lds_dma16(tabg + (inr0 + 28 - 2 * kt) * 63 + lane * 4,
                    smem + TR_OFF + nbuf * 2048);
        else
          lds_dma16(tabg + (inr0 + 28 - 2 * kt) * 63 + 256 + lane * 4,
                    smem + TR_OFF + nbuf * 2048 + 1024);
      }
    }
    const short* Kl = (const short*)(smem + K0_OFF + buf * 8192);
    const short* Vl = (const short*)(smem + V0_OFF + buf * 6144);
    const float* Tl = (const float*)(smem + TR_OFF + buf * 2048);

    // S^T = mfma(K-frag, Q-frag) with bias strip as accumulator init
    float s[4][4];
    __builtin_amdgcn_s_setprio(1);
#pragma unroll
    for (int nt = 0; nt < 4; nt++) {
      const float* tn = Tl + tbase - (nt >= 2 ? 63 : 0) - (nt & 1) * 16;
      f32x4 c;
      c[0] = tn[0]; c[1] = tn[-1]; c[2] = tn[-2]; c[3] = tn[-3];
      c = __builtin_amdgcn_mfma_f32_16x16x32_bf16(
          *(const short8*)(Kl + (nt * 16 + lq) * 64 + sw0), qf0, c, 0, 0, 0);
      c = __builtin_amdgcn_mfma_f32_16x16x32_bf16(
          *(const short8*)(Kl + (nt * 16 + lq) * 64 + sw1), qf1, c, 0, 0, 0);
#pragma unroll
      for (int r = 0; r < 4; r++) s[nt][r] = c[r];
    }
    __builtin_amdgcn_s_setprio(0);
    // no-max softmax: exp2 directly (shift-invariant; args bounded ~|8|)
#pragma unroll
    for (int nt = 0; nt < 4; nt++)
#pragma unroll
      for (int r = 0; r < 4; r++) s[nt][r] = exp2f(s[nt][r]);
    // P^T -> bf16 fragments fully in-register (T12):
    uint4v p0, p1;
    {
      unsigned a, bb_;
      a = pk2(s[0][0], s[0][1]); bb_ = pk2(s[1][0], s[1][1]);
      pl16swap(a, bb_); p0[0] = a; p0[2] = bb_;
      a = pk2(s[0][2], s[0][3]); bb_ = pk2(s[1][2], s[1][3]);
      pl16swap(a, bb_); p0[1] = a; p0[3] = bb_;
      a = pk2(s[2][0], s[2][1]); bb_ = pk2(s[3][0], s[3][1]);
      pl16swap(a, bb_); p1[0] = a; p1[2] = bb_;
      a = pk2(s[2][2], s[2][3]); bb_ = pk2(s[3][2], s[3][3]);
      pl16swap(a, bb_); p1[1] = a; p1[3] = bb_;
    }
    short8 pf0 = *(short8*)&p0;
    short8 pf1 = *(short8*)&p1;
    // O^T += mfma(V^T-frag, P^T-frag); L via register-ones A operand
    __builtin_amdgcn_s_setprio(1);
#pragma unroll
    for (int dt = 0; dt < 3; dt++)
      O[dt] = __builtin_amdgcn_mfma_f32_16x16x32_bf16(
          *(const short8*)(Vl + (dt * 16 + lq) * 64 + swv0), pf0, O[dt], 0, 0, 0);
    O[3] = __builtin_amdgcn_mfma_f32_16x16x32_bf16(onesv, pf0, O[3], 0, 0, 0);
#pragma unroll
    for (int dt = 0; dt < 3; dt++)
      O[dt] = __builtin_amdgcn_mfma_f32_16x16x32_bf16(
          *(const short8*)(Vl + (dt * 16 + lq) * 64 + swv1), pf1, O[dt], 0, 0, 0);
    O[3] = __builtin_amdgcn_mfma_f32_16x16x32_bf16(onesv, pf1, O[3], 0, 0, 0);
    __builtin_amdgcn_s_setprio(0);
  }
  // epilogue: write unnormalized partials straight from registers (no LDS, no barrier)
  {
    const int q = q0 + wv * 16 + lq;
    float* op = Opart + (((size_t)(z * 64 + bh) << 10) + q) * 48 + quad * 4;
#pragma unroll
    for (int dt = 0; dt < 3; dt++) *(f32x4*)(op + dt * 16) = O[dt];
    if (quad == 0) Lpart[((size_t)(z * 64 + bh) << 10) + q] = O[3][0];
  }
}

// ---------------- combine partials: AT = (O0+O1)/(L0+L1), bf16 ----------------
__global__ __launch_bounds__(256) void k_comb(
    const float* __restrict__ Opart, const float* __restrict__ Lpart,
    __hip_bfloat16* __restrict__ ATb) {
  const int bh = blockIdx.x, b = bh >> 3, h = bh & 7;
  const int q = blockIdx.y * 64 + (threadIdx.x >> 2);
  const int cg = (threadIdx.x & 3) * 12;
  const size_t r0 = (((size_t)bh << 10) + q) * 48 + cg;
  const size_t r1 = (((size_t)(64 + bh) << 10) + q) * 48 + cg;
  const float inv = 1.0f / (Lpart[((size_t)bh << 10) + q] +
                            Lpart[(size_t)65536 + ((size_t)bh << 10) + q]);
  short outp[12];
#pragma unroll
  for (int g = 0; g < 3; g++) {
    f32x4 a = *(const f32x4*)(Opart + r0 + g * 4);
    f32x4 c = *(const f32x4*)(Opart + r1 + g * 4);
#pragma unroll
    for (int r = 0; r < 4; r++) outp[g * 4 + r] = bf16bits((a[r] + c[r]) * inv);
  }
  short* dst = (short*)ATb + (((size_t)b << 10) + q) * 384 + h * 48 + cg;
  *(short4v*)dst = *(short4v*)outp;
  *(short4v*)(dst + 4) = *(short4v*)(outp + 4);
  *(short4v*)(dst + 8) = *(short4v*)(outp + 8);
}

// ---------------- proj GEMM (bf16 MFMA), swizzled DMA staging ----------------
__global__ __launch_bounds__(256) void k_proj_mfma(
    const __hip_bfloat16* __restrict__ ATb,  // [8][1024][384]
    const __hip_bfloat16* __restrict__ wtp,  // [384][384] ([cout][cin])
    const float* __restrict__ pb, float* __restrict__ out) {
  __shared__ __align__(16) char smem[16384];
  short* As = (short*)smem;
  short* Bs = (short*)(smem + 8192);
  const int c0 = blockIdx.x * 64;
  const int n0 = blockIdx.y * 64;
  const int b = blockIdx.z;
  const int tid = threadIdx.x;
  const int wv = tid >> 6, lane = tid & 63, quad = lane >> 4, lq = lane & 15;
  const int lrow = lane >> 3;
  const int gsw = ((lane & 7) ^ lrow) * 8;
  const int sw0 = (quad ^ (lq & 7)) * 8;
  const int sw1 = sw0 ^ 32;
  f32x4 acc[4];
#pragma unroll
  for (int nt = 0; nt < 4; nt++) acc[nt] = (f32x4){0.f, 0.f, 0.f, 0.f};
  for (int kk = 0; kk < CC; kk += 64) {
    __syncthreads();
    for (int c = wv; c < 16; c += 4) {
      if (c < 8)
        lds_dma16((const short*)wtp + (size_t)(c0 + c * 8 + lrow) * 384 + kk + gsw,
                  smem + c * 1024);
      else
        lds_dma16((const short*)ATb + ((size_t)(b << 10) + n0 + (c - 8) * 8 + lrow) * 384 + kk + gsw,
                  smem + 8192 + (c - 8) * 1024);
    }
    __syncthreads();
    short8 a0 = *(const short8*)(As + (wv * 16 + lq) * 64 + sw0);
    short8 a1 = *(const short8*)(As + (wv * 16 + lq) * 64 + sw1);
#pragma unroll
    for (int nt = 0; nt < 4; nt++) {
      acc[nt] = __builtin_amdgcn_mfma_f32_16x16x32_bf16(
          a0, *(const short8*)(Bs + (nt * 16 + lq) * 64 + sw0), acc[nt], 0, 0, 0);
      acc[nt] = __builtin_amdgcn_mfma_f32_16x16x32_bf16(
          a1, *(const short8*)(Bs + (nt * 16 + lq) * 64 + sw1), acc[nt], 0, 0, 0);
    }
  }
#pragma unroll
  for (int nt = 0; nt < 4; nt++) {
    int n = n0 + nt * 16 + lq;
#pragma unroll
    for (int r = 0; r < 4; r++) {
      int c = c0 + wv * 16 + quad * 4 + r;
      out[((size_t)b * 384 + c) * 1024 + n] = acc[nt][r] + pb[c];
    }
  }
}

extern "C" void kernel_launch(void* const* d_in, const int* in_sizes, int n_in,
                              void* d_out, int out_size, void* d_ws, size_t ws_size,
                              hipStream_t stream) {
  const float* x = (const float*)d_in[0];
  const float* qkv_w = (const float*)d_in[1];
  const float* qkv_b = (const float*)d_in[2];
  const float* proj_w = (const float*)d_in[3];
  const float* proj_b = (const float*)d_in[4];
  const float* w1 = (const float*)d_in[5];
  const float* b1 = (const float*)d_in[6];
  const float* w2 = (const float*)d_in[7];
  const float* b2 = (const float*)d_in[8];
  float* out = (float*)d_out;

  char* w = (char*)d_ws;
  __hip_bfloat16* xt = (__hip_bfloat16*)w;   w += (size_t)8192 * 384 * 2;
  __hip_bfloat16* wtq = (__hip_bfloat16*)w;  w += (size_t)1152 * 384 * 2;
  __hip_bfloat16* wtp = (__hip_bfloat16*)w;  w += (size_t)384 * 384 * 2;
  __hip_bfloat16* Qb = (__hip_bfloat16*)w;   w += (size_t)64 * 1024 * 64 * 2;
  __hip_bfloat16* Kb = (__hip_bfloat16*)w;   w += (size_t)64 * 1024 * 64 * 2;
  __hip_bfloat16* Vt = (__hip_bfloat16*)w;   w += (size_t)64 * 48 * 1024 * 2;
  __hip_bfloat16* ATb = (__hip_bfloat16*)w;  w += (size_t)8192 * 384 * 2;
  float* tab = (float*)w;                    w += (size_t)8 * 3969 * 4 + 1024;  // +1KB DMA slack
  float* Opart = (float*)w;                  w += (size_t)2 * 64 * 1024 * 48 * 4;
  float* Lpart = (float*)w;                  w += (size_t)2 * 64 * 1024 * 4;

  k_prep<<<dim3(3773), dim3(256), 0, stream>>>(x, qkv_w, proj_w, w1, b1, w2, b2,
                                               xt, wtq, wtp, tab);
  k_qkv_mfma<<<dim3(9, 128), dim3(512), 0, stream>>>(xt, wtq, qkv_b, Qb, Kb, Vt);
  k_flash<<<dim3(64, 8, 2), dim3(512), 0, stream>>>(Qb, Kb, Vt, tab, Opart, Lpart);
  k_comb<<<dim3(64, 16), dim3(256), 0, stream>>>(Opart, Lpart, ATb);
  k_proj_mfma<<<dim3(6, 16, 8), dim3(256), 0, stream>>>(ATb, wtp, proj_b, out);
}

// Round 9
// 161.567 us; speedup vs baseline: 1.0807x; 1.0807x over previous
//
#include <hip/hip_runtime.h>
#include <hip/hip_bf16.h>
#include <math.h>

#define BB 8
#define CC 384
#define NT 1024
#define NHEAD 8
#define HD 48
#define HIDDEN 192
#define THREEC 1152

typedef short short8 __attribute__((ext_vector_type(8)));
typedef short short4v __attribute__((ext_vector_type(4)));
typedef float f32x4 __attribute__((ext_vector_type(4)));
typedef unsigned int uint2v __attribute__((ext_vector_type(2)));
typedef unsigned int uint4v __attribute__((ext_vector_type(4)));

static __device__ __forceinline__ short bf16bits(float v) {
  __hip_bfloat16 h = __float2bfloat16(v);
  return *(short*)&h;
}
// pack two fp32 -> two bf16 (round-half-up) in 3 ops via v_perm_b32
static __device__ __forceinline__ unsigned pk2(float a, float b) {
  return __builtin_amdgcn_perm(__float_as_uint(b) + 0x8000u,
                               __float_as_uint(a) + 0x8000u, 0x07060302u);
}
// async global->LDS DMA, 16B per lane; LDS dest = base + lane*16
static __device__ __forceinline__ void lds_dma16(const void* g, void* l) {
  __builtin_amdgcn_global_load_lds((const __attribute__((address_space(1))) unsigned*)g,
                                   (__attribute__((address_space(3))) unsigned*)l, 16, 0, 0);
}
// gfx950 cross-lane: A'=[A0,B0,A2,B2], B'=[A1,B1,A3,B3] (16-lane rows)
static __device__ __forceinline__ void pl16swap(unsigned& a, unsigned& b) {
  asm("v_permlane16_swap_b32 %0, %1" : "+v"(a), "+v"(b));
}
// raw v_exp_f32 (D = 2^S0): args bounded |x|<~15 here, so ocml's range/denorm
// fixup (~4-6 VALU per call) is dead weight on the busiest pipe.
static __device__ __forceinline__ float exp2_raw(float x) {
  float r;
  asm("v_exp_f32 %0, %1" : "=v"(r) : "v"(x));
  return r;
}

// ---------------- fused prep: x/wq/wp transposes + bias table, one launch ----------------
// blocks [0,3072): x transpose; [3072,3504): qkv_w; [3504,3648): proj_w; [3648,3773): bias
__global__ __launch_bounds__(256) void k_prep(
    const float* __restrict__ x, const float* __restrict__ qkv_w,
    const float* __restrict__ proj_w,
    const float* __restrict__ w1, const float* __restrict__ b1,
    const float* __restrict__ w2, const float* __restrict__ b2,
    __hip_bfloat16* __restrict__ xt, __hip_bfloat16* __restrict__ wtq,
    __hip_bfloat16* __restrict__ wtp, float* __restrict__ tab) {
  const int bid = blockIdx.x;
  const int tid = threadIdx.x;
  if (bid >= 3648) {  // ---- bias table ----
    int g = (bid - 3648) * 256 + tid;
    int p = g >> 3, jc = g & 7;
    if (p >= 63 * 63) return;
    float rh = (float)(p / 63 - 31) * (1.0f / 31.0f);
    float rw = (float)(p % 63 - 31) * (1.0f / 31.0f);
    float acc[8] = {0.f, 0.f, 0.f, 0.f, 0.f, 0.f, 0.f, 0.f};
    const int j0 = jc * 24;
#pragma unroll 4
    for (int j = j0; j < j0 + 24; j++) {
      float pre = fmaf(rh, w1[j], fmaf(rw, w1[HIDDEN + j], b1[j]));
      float gl = 0.5f * pre * (1.0f + erff(pre * 0.70710678118654752f));
#pragma unroll
      for (int h = 0; h < 8; h++) acc[h] = fmaf(gl, w2[j * 8 + h], acc[h]);
    }
#pragma unroll
    for (int msk = 1; msk <= 4; msk <<= 1)
#pragma unroll
      for (int h = 0; h < 8; h++) acc[h] += __shfl_xor(acc[h], msk);
    if (jc == 0) {
#pragma unroll
      for (int h = 0; h < 8; h++)
        tab[h * 3969 + p] = (acc[h] + b2[h]) * 1.4426950408889634f;
    }
    return;
  }
  // ---- transposes ----
  const float* src;
  __hip_bfloat16* dst;
  int R, C, r0, c0;
  if (bid < 3072) {
    int zi = bid / 384, rem = bid % 384;
    R = 384; C = 1024;
    r0 = (rem / 32) * 32; c0 = (rem % 32) * 32;
    src = x + (size_t)zi * R * C;
    dst = xt + (size_t)zi * R * C;
  } else if (bid < 3504) {
    int i = bid - 3072;
    R = 384; C = 1152;
    r0 = (i / 36) * 32; c0 = (i % 36) * 32;
    src = qkv_w; dst = wtq;
  } else {
    int i = bid - 3504;
    R = 384; C = 384;
    r0 = (i / 12) * 32; c0 = (i % 12) * 32;
    src = proj_w; dst = wtp;
  }
  __shared__ float t[32][33];
#pragma unroll
  for (int e = 0; e < 4; e++) {
    int i = tid + e * 256;
    int r = i >> 5, c = i & 31;
    t[r][c] = src[(size_t)(r0 + r) * C + c0 + c];
  }
  __syncthreads();
#pragma unroll
  for (int e = 0; e < 4; e++) {
    int i = tid + e * 256;
    int c = i >> 5, r = i & 31;
    dst[(size_t)(c0 + c) * R + r0 + r] = __float2bfloat16(t[r][c]);
  }
}

// ---------------- QKV GEMM (bf16 MFMA), swizzled DMA staging ----------------
__global__ __launch_bounds__(256) void k_qkv_mfma(
    const __hip_bfloat16* __restrict__ xt,   // [8192][384]
    const __hip_bfloat16* __restrict__ wtq,  // [1152][384]
    const float* __restrict__ qkv_b,
    __hip_bfloat16* __restrict__ Qb,  // [64][1024][64], d-pad zeroed here
    __hip_bfloat16* __restrict__ Kb,  // [64][1024][64], d-pad zeroed here
    __hip_bfloat16* __restrict__ Vt)  // [64][48][1024]
{
  __shared__ __align__(16) char smem[17408];
  short* As = (short*)smem;           // 64x64 shorts, swizzled
  short* Bs = (short*)(smem + 8192);  // 64x64 shorts, swizzled
  float* Vf = (float*)smem;           // 64x68 f32 reuse
  const int n0 = blockIdx.x * 64;  // out-channel tile (fastest: 18 blocks share x-tile)
  const int m0 = blockIdx.y * 64;  // token tile
  const int tid = threadIdx.x;
  const int wv = tid >> 6, lane = tid & 63, quad = lane >> 4, lq = lane & 15;
  const int lrow = lane >> 3;
  const int gsw = ((lane & 7) ^ lrow) * 8;
  const int sw0 = (quad ^ (lq & 7)) * 8;
  const int sw1 = sw0 ^ 32;
  f32x4 acc[4];
#pragma unroll
  for (int nt = 0; nt < 4; nt++) acc[nt] = (f32x4){0.f, 0.f, 0.f, 0.f};
  for (int kk = 0; kk < CC; kk += 64) {
    __syncthreads();
    for (int c = wv; c < 16; c += 4) {
      if (c < 8)
        lds_dma16((const short*)xt + (size_t)(m0 + c * 8 + lrow) * 384 + kk + gsw,
                  smem + c * 1024);
      else
        lds_dma16((const short*)wtq + (size_t)(n0 + (c - 8) * 8 + lrow) * 384 + kk + gsw,
                  smem + 8192 + (c - 8) * 1024);
    }
    __syncthreads();
    short8 a0 = *(const short8*)(As + (wv * 16 + lq) * 64 + sw0);
    short8 a1 = *(const short8*)(As + (wv * 16 + lq) * 64 + sw1);
#pragma unroll
    for (int nt = 0; nt < 4; nt++) {
      acc[nt] = __builtin_amdgcn_mfma_f32_16x16x32_bf16(
          a0, *(const short8*)(Bs + (nt * 16 + lq) * 64 + sw0), acc[nt], 0, 0, 0);
      acc[nt] = __builtin_amdgcn_mfma_f32_16x16x32_bf16(
          a1, *(const short8*)(Bs + (nt * 16 + lq) * 64 + sw1), acc[nt], 0, 0, 0);
    }
  }
  __syncthreads();
  const float qscale = 0.14433756729740643f * 1.4426950408889634f;  // 48^-.5 * log2e
  const float sc = (n0 < 384) ? qscale : 1.0f;
#pragma unroll
  for (int nt = 0; nt < 4; nt++) {
    float bias = qkv_b[n0 + nt * 16 + lq];
#pragma unroll
    for (int r = 0; r < 4; r++)
      Vf[(nt * 16 + lq) * 68 + wv * 16 + quad * 4 + r] = (acc[nt][r] + bias) * sc;
  }
  __syncthreads();
  if (n0 >= 768) {
    // ---- V: transposed write [bh][d][n], 32B/thread ----
    int ch = tid & 63, grp = tid >> 6;
    int cg = n0 - 768 + ch;
    int head = cg / 48, d = cg - head * 48;
    int b = m0 >> 10;
    int n = (m0 & 1023) + grp * 16;
    const float* src = Vf + ch * 68 + grp * 16;
    short o16[16];
#pragma unroll
    for (int k = 0; k < 16; k++) o16[k] = bf16bits(src[k]);
    short* dst = (short*)Vt + ((size_t)(b * 8 + head) * 48 + d) * 1024 + n;
    *(short8*)dst = *(short8*)o16;
    *(short8*)(dst + 8) = *(short8*)(o16 + 8);
  } else {
    // ---- Q or K: row-major [bh][n][d], 32B/thread + d-pad zeros ----
    const int which = n0 >= 384;
    short* Out = which ? (short*)Kb : (short*)Qb;
    int n_l = tid & 63, seg = tid >> 6;
    int rr0 = (n0 - which * 384) + seg * 16;  // 16-aligned; 48=3*16 -> no head split
    int head = rr0 / 48, d0 = rr0 - head * 48;
    int b = m0 >> 10;
    int n_g = (m0 & 1023) + n_l;
    const float* src = Vf + (seg * 16) * 68 + n_l;
    short o16[16];
#pragma unroll
    for (int k = 0; k < 16; k++) o16[k] = bf16bits(src[k * 68]);
    short* dst = Out + (((size_t)(b * 8 + head) << 10) + n_g) * 64 + d0;
    *(short8*)dst = *(short8*)o16;
    *(short8*)(dst + 8) = *(short8*)(o16 + 8);
    if (d0 == 0) {
      short8 z = (short8){0, 0, 0, 0, 0, 0, 0, 0};
      *(short8*)(dst + 48) = z;
      *(short8*)(dst + 56) = z;
    }
  }
}

// ---------------- fused flash attention (R6 structure: QBLK=128, 8-wave blocks) ----------------
// One K/V/bias staging feeds 128 q-rows. Per-wave code = R1-proven version.
// R9: exp2f -> raw v_exp_f32 (args bounded; drops ocml fixup VALU on busiest pipe).
#define K0_OFF 0       // K dbuf: 2 x 8192
#define V0_OFF 16384   // V dbuf: 2 x 6144
#define TR_OFF 28672   // tab strips: 2 x 2048
#define SMEM_SZ 32768
__global__ __launch_bounds__(512, 4) void k_flash(
    const __hip_bfloat16* __restrict__ Qb, const __hip_bfloat16* __restrict__ Kb,
    const __hip_bfloat16* __restrict__ Vt, const float* __restrict__ tab,
    __hip_bfloat16* __restrict__ ATb)  // [8][1024][384]
{
  __shared__ __align__(16) char smem[SMEM_SZ];
  float* Os = (float*)smem;

  const int tid = threadIdx.x;
  const int wv = tid >> 6, lane = tid & 63, quad = lane >> 4, lq = lane & 15;
  const int bh = blockIdx.x;
  const int q0 = blockIdx.y * 128;
  const int b = bh >> 3, h = bh & 7;
  const int inr0 = q0 >> 5;

  const int nrow = q0 + wv * 16 + lq;
  const int jnr = nrow & 31;
  // strip for iter it is loaded from global tab row (inr0 + 30 - 2it);
  // local strip row L = rloc - (nt>=2) maps to global row 31 + (nrow>>5) - (key>>5)
  const int rloc = (nrow >> 5) - inr0 + 1;  // in {1..4}
  // tab strip dword index for (nt,r): tbase - (nt>=2)*63 - (nt&1)*16 - r
  const int tbase = rloc * 63 + jnr + 31 - 4 * quad;  // max 314 < 512

  short8 qf0, qf1;
  {
    const short* qp = (const short*)Qb + ((size_t)(bh << 10) + nrow) * 64;
    qf0 = *(const short8*)(qp + quad * 8);
    qf1 = *(const short8*)(qp + 32 + quad * 8);
  }
  short8 onesv;
#pragma unroll
  for (int j = 0; j < 8; j++) onesv[j] = (short)0x3F80;  // bf16(1.0)

  f32x4 O[4];  // O[3] = L accumulator
#pragma unroll
  for (int dt = 0; dt < 4; dt++) O[dt] = (f32x4){0.f, 0.f, 0.f, 0.f};

  const short* kgp = (const short*)Kb + ((size_t)(bh << 10)) * 64;
  const short* vgp = (const short*)Vt + (size_t)bh * 48 * 1024;
  const float* tabg = tab + h * 3969;
  const int lrow = lane >> 3;
  const int gsw = ((lane & 7) ^ lrow) * 8;
  const int sw0 = (quad ^ (lq & 7)) * 8;
  const int sw1 = sw0 ^ 32;
  // V-read swizzle carries the permlane key-permutation (quad -> vq)
  const int vq = ((quad & 1) << 1) | (quad >> 1);
  const int swv0 = (vq ^ (lq & 7)) * 8;
  const int swv1 = swv0 ^ 32;

  // prologue: DMA tile 0 + tab strip 0 (rows inr0+30 ..) -> buf0
  // 16 units: 8x K, 6x V, 2x tab (8 waves x 2 units each)
  for (int c = wv; c < 16; c += 8) {
    if (c < 8)
      lds_dma16(kgp + (size_t)(c * 8 + lrow) * 64 + gsw, smem + K0_OFF + c * 1024);
    else if (c < 14)
      lds_dma16(vgp + (size_t)((c - 8) * 8 + lrow) * 1024 + gsw,
                smem + V0_OFF + (c - 8) * 1024);
    else if (c == 14)
      lds_dma16(tabg + (inr0 + 30) * 63 + lane * 4, smem + TR_OFF);
    else
      lds_dma16(tabg + (inr0 + 30) * 63 + 256 + lane * 4, smem + TR_OFF + 1024);
  }

  for (int it = 0; it < 16; it++) {
    const int m0 = it * 64;
    const int buf = it & 1;
    __syncthreads();  // drains tile-it DMA (vmcnt0 + barrier)
    if (it < 15) {    // prefetch tile it+1 into the other buffer
      const int nbuf = buf ^ 1;
      const int mn = m0 + 64;
      for (int c = wv; c < 16; c += 8) {
        if (c < 8)
          lds_dma16(kgp + (size_t)(mn + c * 8 + lrow) * 64 + gsw,
                    smem + K0_OFF + nbuf * 8192 + c * 1024);
        else if (c < 14)
          lds_dma16(vgp + (size_t)((c - 8) * 8 + lrow) * 1024 + mn + gsw,
                    smem + V0_OFF + nbuf * 6144 + (c - 8) * 1024);
        else if (c == 14)
          lds_dma16(tabg + (inr0 + 28 - 2 * it) * 63 + lane * 4,
                    smem + TR_OFF + nbuf * 2048);
        else
          lds_dma16(tabg + (inr0 + 28 - 2 * it) * 63 + 256 + lane * 4,
                    smem + TR_OFF + nbuf * 2048 + 1024);
      }
    }
    const short* Kl = (const short*)(smem + K0_OFF + buf * 8192);
    const short* Vl = (const short*)(smem + V0_OFF + buf * 6144);
    const float* Tl = (const float*)(smem + TR_OFF + buf * 2048);

    // S^T = mfma(K-frag, Q-frag) with bias strip as accumulator init
    float s[4][4];
    __builtin_amdgcn_s_setprio(1);
#pragma unroll
    for (int nt = 0; nt < 4; nt++) {
      const float* tn = Tl + tbase - (nt >= 2 ? 63 : 0) - (nt & 1) * 16;
      f32x4 c;
      c[0] = tn[0]; c[1] = tn[-1]; c[2] = tn[-2]; c[3] = tn[-3];
      c = __builtin_amdgcn_mfma_f32_16x16x32_bf16(
          *(const short8*)(Kl + (nt * 16 + lq) * 64 + sw0), qf0, c, 0, 0, 0);
      c = __builtin_amdgcn_mfma_f32_16x16x32_bf16(
          *(const short8*)(Kl + (nt * 16 + lq) * 64 + sw1), qf1, c, 0, 0, 0);
#pragma unroll
      for (int r = 0; r < 4; r++) s[nt][r] = c[r];
    }
    __builtin_amdgcn_s_setprio(0);
    // no-max softmax: raw v_exp_f32 (shift-invariant; args bounded ~|15|)
#pragma unroll
    for (int nt = 0; nt < 4; nt++)
#pragma unroll
      for (int r = 0; r < 4; r++) s[nt][r] = exp2_raw(s[nt][r]);
    // P^T -> bf16 fragments fully in-register (T12):
    uint4v p0, p1;
    {
      unsigned a, bb_;
      a = pk2(s[0][0], s[0][1]); bb_ = pk2(s[1][0], s[1][1]);
      pl16swap(a, bb_); p0[0] = a; p0[2] = bb_;
      a = pk2(s[0][2], s[0][3]); bb_ = pk2(s[1][2], s[1][3]);
      pl16swap(a, bb_); p0[1] = a; p0[3] = bb_;
      a = pk2(s[2][0], s[2][1]); bb_ = pk2(s[3][0], s[3][1]);
      pl16swap(a, bb_); p1[0] = a; p1[2] = bb_;
      a = pk2(s[2][2], s[2][3]); bb_ = pk2(s[3][2], s[3][3]);
      pl16swap(a, bb_); p1[1] = a; p1[3] = bb_;
    }
    short8 pf0 = *(short8*)&p0;
    short8 pf1 = *(short8*)&p1;
    // O^T += mfma(V^T-frag, P^T-frag); L via register-ones A operand
    __builtin_amdgcn_s_setprio(1);
#pragma unroll
    for (int dt = 0; dt < 3; dt++)
      O[dt] = __builtin_amdgcn_mfma_f32_16x16x32_bf16(
          *(const short8*)(Vl + (dt * 16 + lq) * 64 + swv0), pf0, O[dt], 0, 0, 0);
    O[3] = __builtin_amdgcn_mfma_f32_16x16x32_bf16(onesv, pf0, O[3], 0, 0, 0);
#pragma unroll
    for (int dt = 0; dt < 3; dt++)
      O[dt] = __builtin_amdgcn_mfma_f32_16x16x32_bf16(
          *(const short8*)(Vl + (dt * 16 + lq) * 64 + swv1), pf1, O[dt], 0, 0, 0);
    O[3] = __builtin_amdgcn_mfma_f32_16x16x32_bf16(onesv, pf1, O[3], 0, 0, 0);
    __builtin_amdgcn_s_setprio(0);
  }
  float inv = 1.0f / O[3][0];  // L(q = wv*16+lq), no shuffle
  __syncthreads();             // all PV reads done before Os aliases buffers
#pragma unroll
  for (int dt = 0; dt < 3; dt++)
#pragma unroll
    for (int r = 0; r < 4; r++)
      Os[(wv * 16 + lq) * 52 + dt * 16 + quad * 4 + r] = O[dt][r] * inv;
  __syncthreads();
  {
    int row = tid >> 2, cg = (tid & 3) * 12;  // 512 thr -> rows 0..127
    const float* src = Os + row * 52 + cg;
    short outp[12];
#pragma unroll
    for (int k = 0; k < 12; k++) outp[k] = bf16bits(src[k]);
    short* dst = (short*)ATb + ((size_t)(b << 10) + q0 + row) * 384 + h * 48 + cg;
    *(short4v*)dst = *(short4v*)outp;
    *(short4v*)(dst + 4) = *(short4v*)(outp + 4);
    *(short4v*)(dst + 8) = *(short4v*)(outp + 8);
  }
}

// ---------------- proj GEMM (bf16 MFMA), swizzled DMA staging ----------------
__global__ __launch_bounds__(256) void k_proj_mfma(
    const __hip_bfloat16* __restrict__ ATb,  // [8][1024][384]
    const __hip_bfloat16* __restrict__ wtp,  // [384][384] ([cout][cin])
    const float* __restrict__ pb, float* __restrict__ out) {
  __shared__ __align__(16) char smem[16384];
  short* As = (short*)smem;
  short* Bs = (short*)(smem + 8192);
  const int c0 = blockIdx.x * 64;
  const int n0 = blockIdx.y * 64;
  const int b = blockIdx.z;
  const int tid = threadIdx.x;
  const int wv = tid >> 6, lane = tid & 63, quad = lane >> 4, lq = lane & 15;
  const int lrow = lane >> 3;
  const int gsw = ((lane & 7) ^ lrow) * 8;
  const int sw0 = (quad ^ (lq & 7)) * 8;
  const int sw1 = sw0 ^ 32;
  f32x4 acc[4];
#pragma unroll
  for (int nt = 0; nt < 4; nt++) acc[nt] = (f32x4){0.f, 0.f, 0.f, 0.f};
  for (int kk = 0; kk < CC; kk += 64) {
    __syncthreads();
    for (int c = wv; c < 16; c += 4) {
      if (c < 8)
        lds_dma16((const short*)wtp + (size_t)(c0 + c * 8 + lrow) * 384 + kk + gsw,
                  smem + c * 1024);
      else
        lds_dma16((const short*)ATb + ((size_t)(b << 10) + n0 + (c - 8) * 8 + lrow) * 384 + kk + gsw,
                  smem + 8192 + (c - 8) * 1024);
    }
    __syncthreads();
    short8 a0 = *(const short8*)(As + (wv * 16 + lq) * 64 + sw0);
    short8 a1 = *(const short8*)(As + (wv * 16 + lq) * 64 + sw1);
#pragma unroll
    for (int nt = 0; nt < 4; nt++) {
      acc[nt] = __builtin_amdgcn_mfma_f32_16x16x32_bf16(
          a0, *(const short8*)(Bs + (nt * 16 + lq) * 64 + sw0), acc[nt], 0, 0, 0);
      acc[nt] = __builtin_amdgcn_mfma_f32_16x16x32_bf16(
          a1, *(const short8*)(Bs + (nt * 16 + lq) * 64 + sw1), acc[nt], 0, 0, 0);
    }
  }
#pragma unroll
  for (int nt = 0; nt < 4; nt++) {
    int n = n0 + nt * 16 + lq;
#pragma unroll
    for (int r = 0; r < 4; r++) {
      int c = c0 + wv * 16 + quad * 4 + r;
      out[((size_t)b * 384 + c) * 1024 + n] = acc[nt][r] + pb[c];
    }
  }
}

extern "C" void kernel_launch(void* const* d_in, const int* in_sizes, int n_in,
                              void* d_out, int out_size, void* d_ws, size_t ws_size,
                              hipStream_t stream) {
  const float* x = (const float*)d_in[0];
  const float* qkv_w = (const float*)d_in[1];
  const float* qkv_b = (const float*)d_in[2];
  const float* proj_w = (const float*)d_in[3];
  const float* proj_b = (const float*)d_in[4];
  const float* w1 = (const float*)d_in[5];
  const float* b1 = (const float*)d_in[6];
  const float* w2 = (const float*)d_in[7];
  const float* b2 = (const float*)d_in[8];
  float* out = (float*)d_out;

  char* w = (char*)d_ws;
  __hip_bfloat16* xt = (__hip_bfloat16*)w;   w += (size_t)8192 * 384 * 2;
  __hip_bfloat16* wtq = (__hip_bfloat16*)w;  w += (size_t)1152 * 384 * 2;
  __hip_bfloat16* wtp = (__hip_bfloat16*)w;  w += (size_t)384 * 384 * 2;
  __hip_bfloat16* Qb = (__hip_bfloat16*)w;   w += (size_t)64 * 1024 * 64 * 2;
  __hip_bfloat16* Kb = (__hip_bfloat16*)w;   w += (size_t)64 * 1024 * 64 * 2;
  __hip_bfloat16* Vt = (__hip_bfloat16*)w;   w += (size_t)64 * 48 * 1024 * 2;
  __hip_bfloat16* ATb = (__hip_bfloat16*)w;  w += (size_t)8192 * 384 * 2;
  float* tab = (float*)w;                    w += (size_t)8 * 3969 * 4 + 1024;  // +1KB DMA slack

  k_prep<<<dim3(3773), dim3(256), 0, stream>>>(x, qkv_w, proj_w, w1, b1, w2, b2,
                                               xt, wtq, wtp, tab);
  k_qkv_mfma<<<dim3(18, 128), dim3(256), 0, stream>>>(xt, wtq, qkv_b, Qb, Kb, Vt);
  k_flash<<<dim3(64, 8), dim3(512), 0, stream>>>(Qb, Kb, Vt, tab, ATb);
  k_proj_mfma<<<dim3(6, 16, 8), dim3(256), 0, stream>>>(ATb, wtp, proj_b, out);
}

// Round 10
// 154.655 us; speedup vs baseline: 1.1290x; 1.0447x over previous
//
#include <hip/hip_runtime.h>
#include <hip/hip_bf16.h>
#include <math.h>

#define BB 8
#define CC 384
#define NT 1024
#define NHEAD 8
#define HD 48
#define HIDDEN 192
#define THREEC 1152

typedef short short8 __attribute__((ext_vector_type(8)));
typedef short short4v __attribute__((ext_vector_type(4)));
typedef float f32x4 __attribute__((ext_vector_type(4)));
typedef unsigned int uint2v __attribute__((ext_vector_type(2)));
typedef unsigned int uint4v __attribute__((ext_vector_type(4)));

static __device__ __forceinline__ short bf16bits(float v) {
  __hip_bfloat16 h = __float2bfloat16(v);
  return *(short*)&h;
}
// pack two fp32 -> two bf16 (round-half-up) in 3 ops via v_perm_b32
static __device__ __forceinline__ unsigned pk2(float a, float b) {
  return __builtin_amdgcn_perm(__float_as_uint(b) + 0x8000u,
                               __float_as_uint(a) + 0x8000u, 0x07060302u);
}
// HW pack: low16 = bf16(lo), high16 = bf16(hi), single VALU instr (RNE)
static __device__ __forceinline__ unsigned cvtpk(float lo, float hi) {
  unsigned r;
  asm("v_cvt_pk_bf16_f32 %0, %1, %2" : "=v"(r) : "v"(lo), "v"(hi));
  return r;
}
// async global->LDS DMA, 16B per lane; LDS dest = base + lane*16
static __device__ __forceinline__ void lds_dma16(const void* g, void* l) {
  __builtin_amdgcn_global_load_lds((const __attribute__((address_space(1))) unsigned*)g,
                                   (__attribute__((address_space(3))) unsigned*)l, 16, 0, 0);
}
// gfx950 cross-lane: A'=[A0,B0,A2,B2], B'=[A1,B1,A3,B3] (16-lane rows)
static __device__ __forceinline__ void pl16swap(unsigned& a, unsigned& b) {
  asm("v_permlane16_swap_b32 %0, %1" : "+v"(a), "+v"(b));
}
// raw v_exp_f32 (D = 2^S0): args bounded |x|<~15 here, so ocml's range/denorm
// fixup (~4-6 VALU per call) is dead weight on the busiest pipe.
static __device__ __forceinline__ float exp2_raw(float x) {
  float r;
  asm("v_exp_f32 %0, %1" : "=v"(r) : "v"(x));
  return r;
}

// ---------------- fused prep: x/wq/wp transposes + bias table, one launch ----------------
// blocks [0,3072): x transpose; [3072,3504): qkv_w; [3504,3648): proj_w; [3648,3773): bias
__global__ __launch_bounds__(256) void k_prep(
    const float* __restrict__ x, const float* __restrict__ qkv_w,
    const float* __restrict__ proj_w,
    const float* __restrict__ w1, const float* __restrict__ b1,
    const float* __restrict__ w2, const float* __restrict__ b2,
    __hip_bfloat16* __restrict__ xt, __hip_bfloat16* __restrict__ wtq,
    __hip_bfloat16* __restrict__ wtp, float* __restrict__ tab) {
  const int bid = blockIdx.x;
  const int tid = threadIdx.x;
  if (bid >= 3648) {  // ---- bias table ----
    int g = (bid - 3648) * 256 + tid;
    int p = g >> 3, jc = g & 7;
    if (p >= 63 * 63) return;
    float rh = (float)(p / 63 - 31) * (1.0f / 31.0f);
    float rw = (float)(p % 63 - 31) * (1.0f / 31.0f);
    float acc[8] = {0.f, 0.f, 0.f, 0.f, 0.f, 0.f, 0.f, 0.f};
    const int j0 = jc * 24;
#pragma unroll 4
    for (int j = j0; j < j0 + 24; j++) {
      float pre = fmaf(rh, w1[j], fmaf(rw, w1[HIDDEN + j], b1[j]));
      float gl = 0.5f * pre * (1.0f + erff(pre * 0.70710678118654752f));
#pragma unroll
      for (int h = 0; h < 8; h++) acc[h] = fmaf(gl, w2[j * 8 + h], acc[h]);
    }
#pragma unroll
    for (int msk = 1; msk <= 4; msk <<= 1)
#pragma unroll
      for (int h = 0; h < 8; h++) acc[h] += __shfl_xor(acc[h], msk);
    if (jc == 0) {
#pragma unroll
      for (int h = 0; h < 8; h++)
        tab[h * 3969 + p] = (acc[h] + b2[h]) * 1.4426950408889634f;
    }
    return;
  }
  // ---- transposes ----
  const float* src;
  __hip_bfloat16* dst;
  int R, C, r0, c0;
  if (bid < 3072) {
    int zi = bid / 384, rem = bid % 384;
    R = 384; C = 1024;
    r0 = (rem / 32) * 32; c0 = (rem % 32) * 32;
    src = x + (size_t)zi * R * C;
    dst = xt + (size_t)zi * R * C;
  } else if (bid < 3504) {
    int i = bid - 3072;
    R = 384; C = 1152;
    r0 = (i / 36) * 32; c0 = (i % 36) * 32;
    src = qkv_w; dst = wtq;
  } else {
    int i = bid - 3504;
    R = 384; C = 384;
    r0 = (i / 12) * 32; c0 = (i % 12) * 32;
    src = proj_w; dst = wtp;
  }
  __shared__ float t[32][33];
#pragma unroll
  for (int e = 0; e < 4; e++) {
    int i = tid + e * 256;
    int r = i >> 5, c = i & 31;
    t[r][c] = src[(size_t)(r0 + r) * C + c0 + c];
  }
  __syncthreads();
#pragma unroll
  for (int e = 0; e < 4; e++) {
    int i = tid + e * 256;
    int c = i >> 5, r = i & 31;
    dst[(size_t)(c0 + c) * R + r0 + r] = __float2bfloat16(t[r][c]);
  }
}

// ---------------- QKV GEMM (bf16 MFMA), swizzled DMA staging ----------------
__global__ __launch_bounds__(256) void k_qkv_mfma(
    const __hip_bfloat16* __restrict__ xt,   // [8192][384]
    const __hip_bfloat16* __restrict__ wtq,  // [1152][384]
    const float* __restrict__ qkv_b,
    __hip_bfloat16* __restrict__ Qb,  // [64][1024][64], d-pad zeroed here
    __hip_bfloat16* __restrict__ Kb,  // [64][1024][64], d-pad zeroed here
    __hip_bfloat16* __restrict__ Vt)  // [64][48][1024]
{
  __shared__ __align__(16) char smem[17408];
  short* As = (short*)smem;           // 64x64 shorts, swizzled
  short* Bs = (short*)(smem + 8192);  // 64x64 shorts, swizzled
  float* Vf = (float*)smem;           // 64x68 f32 reuse
  const int n0 = blockIdx.x * 64;  // out-channel tile (fastest: 18 blocks share x-tile)
  const int m0 = blockIdx.y * 64;  // token tile
  const int tid = threadIdx.x;
  const int wv = tid >> 6, lane = tid & 63, quad = lane >> 4, lq = lane & 15;
  const int lrow = lane >> 3;
  const int gsw = ((lane & 7) ^ lrow) * 8;
  const int sw0 = (quad ^ (lq & 7)) * 8;
  const int sw1 = sw0 ^ 32;
  f32x4 acc[4];
#pragma unroll
  for (int nt = 0; nt < 4; nt++) acc[nt] = (f32x4){0.f, 0.f, 0.f, 0.f};
  for (int kk = 0; kk < CC; kk += 64) {
    __syncthreads();
    for (int c = wv; c < 16; c += 4) {
      if (c < 8)
        lds_dma16((const short*)xt + (size_t)(m0 + c * 8 + lrow) * 384 + kk + gsw,
                  smem + c * 1024);
      else
        lds_dma16((const short*)wtq + (size_t)(n0 + (c - 8) * 8 + lrow) * 384 + kk + gsw,
                  smem + 8192 + (c - 8) * 1024);
    }
    __syncthreads();
    short8 a0 = *(const short8*)(As + (wv * 16 + lq) * 64 + sw0);
    short8 a1 = *(const short8*)(As + (wv * 16 + lq) * 64 + sw1);
#pragma unroll
    for (int nt = 0; nt < 4; nt++) {
      acc[nt] = __builtin_amdgcn_mfma_f32_16x16x32_bf16(
          a0, *(const short8*)(Bs + (nt * 16 + lq) * 64 + sw0), acc[nt], 0, 0, 0);
      acc[nt] = __builtin_amdgcn_mfma_f32_16x16x32_bf16(
          a1, *(const short8*)(Bs + (nt * 16 + lq) * 64 + sw1), acc[nt], 0, 0, 0);
    }
  }
  __syncthreads();
  const float qscale = 0.14433756729740643f * 1.4426950408889634f;  // 48^-.5 * log2e
  const float sc = (n0 < 384) ? qscale : 1.0f;
#pragma unroll
  for (int nt = 0; nt < 4; nt++) {
    float bias = qkv_b[n0 + nt * 16 + lq];
#pragma unroll
    for (int r = 0; r < 4; r++)
      Vf[(nt * 16 + lq) * 68 + wv * 16 + quad * 4 + r] = (acc[nt][r] + bias) * sc;
  }
  __syncthreads();
  if (n0 >= 768) {
    // ---- V: transposed write [bh][d][n], 32B/thread ----
    int ch = tid & 63, grp = tid >> 6;
    int cg = n0 - 768 + ch;
    int head = cg / 48, d = cg - head * 48;
    int b = m0 >> 10;
    int n = (m0 & 1023) + grp * 16;
    const float* src = Vf + ch * 68 + grp * 16;
    short o16[16];
#pragma unroll
    for (int k = 0; k < 16; k++) o16[k] = bf16bits(src[k]);
    short* dst = (short*)Vt + ((size_t)(b * 8 + head) * 48 + d) * 1024 + n;
    *(short8*)dst = *(short8*)o16;
    *(short8*)(dst + 8) = *(short8*)(o16 + 8);
  } else {
    // ---- Q or K: row-major [bh][n][d], 32B/thread + d-pad zeros ----
    const int which = n0 >= 384;
    short* Out = which ? (short*)Kb : (short*)Qb;
    int n_l = tid & 63, seg = tid >> 6;
    int rr0 = (n0 - which * 384) + seg * 16;  // 16-aligned; 48=3*16 -> no head split
    int head = rr0 / 48, d0 = rr0 - head * 48;
    int b = m0 >> 10;
    int n_g = (m0 & 1023) + n_l;
    const float* src = Vf + (seg * 16) * 68 + n_l;
    short o16[16];
#pragma unroll
    for (int k = 0; k < 16; k++) o16[k] = bf16bits(src[k * 68]);
    short* dst = Out + (((size_t)(b * 8 + head) << 10) + n_g) * 64 + d0;
    *(short8*)dst = *(short8*)o16;
    *(short8*)(dst + 8) = *(short8*)(o16 + 8);
    if (d0 == 0) {
      short8 z = (short8){0, 0, 0, 0, 0, 0, 0, 0};
      *(short8*)(dst + 48) = z;
      *(short8*)(dst + 56) = z;
    }
  }
}

// ---------------- fused flash attention (R6 structure: QBLK=128, 8-wave blocks) ----------------
// R9: raw v_exp_f32. R10: cvt_pk_bf16 packing (8 instr vs 24) + pointer-incremented
// DMA staging (per-wave constant strides; no per-iter 64-bit addr recompute).
#define K0_OFF 0       // K dbuf: 2 x 8192
#define V0_OFF 16384   // V dbuf: 2 x 6144
#define TR_OFF 28672   // tab strips: 2 x 2048
#define SMEM_SZ 32768
__global__ __launch_bounds__(512, 4) void k_flash(
    const __hip_bfloat16* __restrict__ Qb, const __hip_bfloat16* __restrict__ Kb,
    const __hip_bfloat16* __restrict__ Vt, const float* __restrict__ tab,
    __hip_bfloat16* __restrict__ ATb)  // [8][1024][384]
{
  __shared__ __align__(16) char smem[SMEM_SZ];
  float* Os = (float*)smem;

  const int tid = threadIdx.x;
  const int wv = tid >> 6, lane = tid & 63, quad = lane >> 4, lq = lane & 15;
  const int bh = blockIdx.x;
  const int q0 = blockIdx.y * 128;
  const int b = bh >> 3, h = bh & 7;
  const int inr0 = q0 >> 5;

  const int nrow = q0 + wv * 16 + lq;
  const int jnr = nrow & 31;
  // strip for iter it is loaded from global tab row (inr0 + 30 - 2it);
  // local strip row L = rloc - (nt>=2) maps to global row 31 + (nrow>>5) - (key>>5)
  const int rloc = (nrow >> 5) - inr0 + 1;  // in {1..4}
  // tab strip dword index for (nt,r): tbase - (nt>=2)*63 - (nt&1)*16 - r
  const int tbase = rloc * 63 + jnr + 31 - 4 * quad;  // max 314 < 512

  short8 qf0, qf1;
  {
    const short* qp = (const short*)Qb + ((size_t)(bh << 10) + nrow) * 64;
    qf0 = *(const short8*)(qp + quad * 8);
    qf1 = *(const short8*)(qp + 32 + quad * 8);
  }
  short8 onesv;
#pragma unroll
  for (int j = 0; j < 8; j++) onesv[j] = (short)0x3F80;  // bf16(1.0)

  f32x4 O[4];  // O[3] = L accumulator
#pragma unroll
  for (int dt = 0; dt < 4; dt++) O[dt] = (f32x4){0.f, 0.f, 0.f, 0.f};

  const short* kgp = (const short*)Kb + ((size_t)(bh << 10)) * 64;
  const short* vgp = (const short*)Vt + (size_t)bh * 48 * 1024;
  const float* tabg = tab + h * 3969;
  const int lrow = lane >> 3;
  const int gsw = ((lane & 7) ^ lrow) * 8;
  const int sw0 = (quad ^ (lq & 7)) * 8;
  const int sw1 = sw0 ^ 32;
  // V-read swizzle carries the permlane key-permutation (quad -> vq)
  const int vq = ((quad & 1) << 1) | (quad >> 1);
  const int swv0 = (vq ^ (lq & 7)) * 8;
  const int swv1 = swv0 ^ 32;

  // per-wave DMA units (16 total: 8x K, 6x V, 2x tab), pointer-incremented:
  //   K unit  : stride +8192 B/tile
  //   V unit  : stride +128 B/tile
  //   tab unit: stride -504 B/tile (row -2 per tile, 63 floats/row)
  const char* ksrc = (const char*)kgp + (((size_t)(wv * 8 + lrow) * 64 + gsw) << 1);
  const int kd = K0_OFF + wv * 1024;
  const char* s2src;
  int s2stride, s2d, s2dalt;
  if (wv < 6) {
    s2src = (const char*)vgp + (((size_t)(wv * 8 + lrow) * 1024 + gsw) << 1);
    s2stride = 128;
    s2d = V0_OFF + wv * 1024;
    s2dalt = 6144;
  } else {
    s2src = (const char*)(tabg + (inr0 + 30) * 63 + lane * 4 + (wv == 7 ? 256 : 0));
    s2stride = -504;
    s2d = TR_OFF + (wv == 7 ? 1024 : 0);
    s2dalt = 2048;
  }
  // prologue: tile 0 -> buf0 (2 DMAs per wave, straight-line)
  lds_dma16(ksrc, smem + kd);
  lds_dma16(s2src, smem + s2d);

  for (int it = 0; it < 16; it++) {
    const int buf = it & 1;
    __syncthreads();  // drains tile-it DMA (vmcnt0 + barrier)
    if (it < 15) {    // prefetch tile it+1 into the other buffer
      const int nbuf = buf ^ 1;
      ksrc += 8192;
      s2src += s2stride;
      lds_dma16(ksrc, smem + kd + nbuf * 8192);
      lds_dma16(s2src, smem + s2d + nbuf * s2dalt);
    }
    const short* Kl = (const short*)(smem + K0_OFF + buf * 8192);
    const short* Vl = (const short*)(smem + V0_OFF + buf * 6144);
    const float* Tl = (const float*)(smem + TR_OFF + buf * 2048);

    // S^T = mfma(K-frag, Q-frag) with bias strip as accumulator init
    float s[4][4];
    __builtin_amdgcn_s_setprio(1);
#pragma unroll
    for (int nt = 0; nt < 4; nt++) {
      const float* tn = Tl + tbase - (nt >= 2 ? 63 : 0) - (nt & 1) * 16;
      f32x4 c;
      c[0] = tn[0]; c[1] = tn[-1]; c[2] = tn[-2]; c[3] = tn[-3];
      c = __builtin_amdgcn_mfma_f32_16x16x32_bf16(
          *(const short8*)(Kl + (nt * 16 + lq) * 64 + sw0), qf0, c, 0, 0, 0);
      c = __builtin_amdgcn_mfma_f32_16x16x32_bf16(
          *(const short8*)(Kl + (nt * 16 + lq) * 64 + sw1), qf1, c, 0, 0, 0);
#pragma unroll
      for (int r = 0; r < 4; r++) s[nt][r] = c[r];
    }
    __builtin_amdgcn_s_setprio(0);
    // no-max softmax: raw v_exp_f32 (shift-invariant; args bounded ~|15|)
#pragma unroll
    for (int nt = 0; nt < 4; nt++)
#pragma unroll
      for (int r = 0; r < 4; r++) s[nt][r] = exp2_raw(s[nt][r]);
    // P^T -> bf16 fragments fully in-register (T12, HW cvt_pk):
    uint4v p0, p1;
    {
      unsigned a, bb_;
      a = cvtpk(s[0][0], s[0][1]); bb_ = cvtpk(s[1][0], s[1][1]);
      pl16swap(a, bb_); p0[0] = a; p0[2] = bb_;
      a = cvtpk(s[0][2], s[0][3]); bb_ = cvtpk(s[1][2], s[1][3]);
      pl16swap(a, bb_); p0[1] = a; p0[3] = bb_;
      a = cvtpk(s[2][0], s[2][1]); bb_ = cvtpk(s[3][0], s[3][1]);
      pl16swap(a, bb_); p1[0] = a; p1[2] = bb_;
      a = cvtpk(s[2][2], s[2][3]); bb_ = cvtpk(s[3][2], s[3][3]);
      pl16swap(a, bb_); p1[1] = a; p1[3] = bb_;
    }
    short8 pf0 = *(short8*)&p0;
    short8 pf1 = *(short8*)&p1;
    // O^T += mfma(V^T-frag, P^T-frag); L via register-ones A operand
    __builtin_amdgcn_s_setprio(1);
#pragma unroll
    for (int dt = 0; dt < 3; dt++)
      O[dt] = __builtin_amdgcn_mfma_f32_16x16x32_bf16(
          *(const short8*)(Vl + (dt * 16 + lq) * 64 + swv0), pf0, O[dt], 0, 0, 0);
    O[3] = __builtin_amdgcn_mfma_f32_16x16x32_bf16(onesv, pf0, O[3], 0, 0, 0);
#pragma unroll
    for (int dt = 0; dt < 3; dt++)
      O[dt] = __builtin_amdgcn_mfma_f32_16x16x32_bf16(
          *(const short8*)(Vl + (dt * 16 + lq) * 64 + swv1), pf1, O[dt], 0, 0, 0);
    O[3] = __builtin_amdgcn_mfma_f32_16x16x32_bf16(onesv, pf1, O[3], 0, 0, 0);
    __builtin_amdgcn_s_setprio(0);
  }
  float inv = 1.0f / O[3][0];  // L(q = wv*16+lq), no shuffle
  __syncthreads();             // all PV reads done before Os aliases buffers
#pragma unroll
  for (int dt = 0; dt < 3; dt++)
#pragma unroll
    for (int r = 0; r < 4; r++)
      Os[(wv * 16 + lq) * 52 + dt * 16 + quad * 4 + r] = O[dt][r] * inv;
  __syncthreads();
  {
    int row = tid >> 2, cg = (tid & 3) * 12;  // 512 thr -> rows 0..127
    const float* src = Os + row * 52 + cg;
    short outp[12];
#pragma unroll
    for (int k = 0; k < 12; k++) outp[k] = bf16bits(src[k]);
    short* dst = (short*)ATb + ((size_t)(b << 10) + q0 + row) * 384 + h * 48 + cg;
    *(short4v*)dst = *(short4v*)outp;
    *(short4v*)(dst + 4) = *(short4v*)(outp + 4);
    *(short4v*)(dst + 8) = *(short4v*)(outp + 8);
  }
}

// ---------------- proj GEMM (bf16 MFMA), swizzled DMA staging ----------------
__global__ __launch_bounds__(256) void k_proj_mfma(
    const __hip_bfloat16* __restrict__ ATb,  // [8][1024][384]
    const __hip_bfloat16* __restrict__ wtp,  // [384][384] ([cout][cin])
    const float* __restrict__ pb, float* __restrict__ out) {
  __shared__ __align__(16) char smem[16384];
  short* As = (short*)smem;
  short* Bs = (short*)(smem + 8192);
  const int c0 = blockIdx.x * 64;
  const int n0 = blockIdx.y * 64;
  const int b = blockIdx.z;
  const int tid = threadIdx.x;
  const int wv = tid >> 6, lane = tid & 63, quad = lane >> 4, lq = lane & 15;
  const int lrow = lane >> 3;
  const int gsw = ((lane & 7) ^ lrow) * 8;
  const int sw0 = (quad ^ (lq & 7)) * 8;
  const int sw1 = sw0 ^ 32;
  f32x4 acc[4];
#pragma unroll
  for (int nt = 0; nt < 4; nt++) acc[nt] = (f32x4){0.f, 0.f, 0.f, 0.f};
  for (int kk = 0; kk < CC; kk += 64) {
    __syncthreads();
    for (int c = wv; c < 16; c += 4) {
      if (c < 8)
        lds_dma16((const short*)wtp + (size_t)(c0 + c * 8 + lrow) * 384 + kk + gsw,
                  smem + c * 1024);
      else
        lds_dma16((const short*)ATb + ((size_t)(b << 10) + n0 + (c - 8) * 8 + lrow) * 384 + kk + gsw,
                  smem + 8192 + (c - 8) * 1024);
    }
    __syncthreads();
    short8 a0 = *(const short8*)(As + (wv * 16 + lq) * 64 + sw0);
    short8 a1 = *(const short8*)(As + (wv * 16 + lq) * 64 + sw1);
#pragma unroll
    for (int nt = 0; nt < 4; nt++) {
      acc[nt] = __builtin_amdgcn_mfma_f32_16x16x32_bf16(
          a0, *(const short8*)(Bs + (nt * 16 + lq) * 64 + sw0), acc[nt], 0, 0, 0);
      acc[nt] = __builtin_amdgcn_mfma_f32_16x16x32_bf16(
          a1, *(const short8*)(Bs + (nt * 16 + lq) * 64 + sw1), acc[nt], 0, 0, 0);
    }
  }
#pragma unroll
  for (int nt = 0; nt < 4; nt++) {
    int n = n0 + nt * 16 + lq;
#pragma unroll
    for (int r = 0; r < 4; r++) {
      int c = c0 + wv * 16 + quad * 4 + r;
      out[((size_t)b * 384 + c) * 1024 + n] = acc[nt][r] + pb[c];
    }
  }
}

extern "C" void kernel_launch(void* const* d_in, const int* in_sizes, int n_in,
                              void* d_out, int out_size, void* d_ws, size_t ws_size,
                              hipStream_t stream) {
  const float* x = (const float*)d_in[0];
  const float* qkv_w = (const float*)d_in[1];
  const float* qkv_b = (const float*)d_in[2];
  const float* proj_w = (const float*)d_in[3];
  const float* proj_b = (const float*)d_in[4];
  const float* w1 = (const float*)d_in[5];
  const float* b1 = (const float*)d_in[6];
  const float* w2 = (const float*)d_in[7];
  const float* b2 = (const float*)d_in[8];
  float* out = (float*)d_out;

  char* w = (char*)d_ws;
  __hip_bfloat16* xt = (__hip_bfloat16*)w;   w += (size_t)8192 * 384 * 2;
  __hip_bfloat16* wtq = (__hip_bfloat16*)w;  w += (size_t)1152 * 384 * 2;
  __hip_bfloat16* wtp = (__hip_bfloat16*)w;  w += (size_t)384 * 384 * 2;
  __hip_bfloat16* Qb = (__hip_bfloat16*)w;   w += (size_t)64 * 1024 * 64 * 2;
  __hip_bfloat16* Kb = (__hip_bfloat16*)w;   w += (size_t)64 * 1024 * 64 * 2;
  __hip_bfloat16* Vt = (__hip_bfloat16*)w;   w += (size_t)64 * 48 * 1024 * 2;
  __hip_bfloat16* ATb = (__hip_bfloat16*)w;  w += (size_t)8192 * 384 * 2;
  float* tab = (float*)w;                    w += (size_t)8 * 3969 * 4 + 1024;  // +1KB DMA slack

  k_prep<<<dim3(3773), dim3(256), 0, stream>>>(x, qkv_w, proj_w, w1, b1, w2, b2,
                                               xt, wtq, wtp, tab);
  k_qkv_mfma<<<dim3(18, 128), dim3(256), 0, stream>>>(xt, wtq, qkv_b, Qb, Kb, Vt);
  k_flash<<<dim3(64, 8), dim3(512), 0, stream>>>(Qb, Kb, Vt, tab, ATb);
  k_proj_mfma<<<dim3(6, 16, 8), dim3(256), 0, stream>>>(ATb, wtp, proj_b, out);
}

// Round 11
// 151.014 us; speedup vs baseline: 1.1563x; 1.0241x over previous
//
#include <hip/hip_runtime.h>
#include <hip/hip_bf16.h>
#include <math.h>

#define BB 8
#define CC 384
#define NT 1024
#define NHEAD 8
#define HD 48
#define HIDDEN 192
#define THREEC 1152

typedef short short8 __attribute__((ext_vector_type(8)));
typedef short short4v __attribute__((ext_vector_type(4)));
typedef float f32x4 __attribute__((ext_vector_type(4)));
typedef unsigned int uint2v __attribute__((ext_vector_type(2)));
typedef unsigned int uint4v __attribute__((ext_vector_type(4)));

static __device__ __forceinline__ short bf16bits(float v) {
  __hip_bfloat16 h = __float2bfloat16(v);
  return *(short*)&h;
}
// HW pack: low16 = bf16(lo), high16 = bf16(hi), single VALU instr (RNE)
static __device__ __forceinline__ unsigned cvtpk(float lo, float hi) {
  unsigned r;
  asm("v_cvt_pk_bf16_f32 %0, %1, %2" : "=v"(r) : "v"(lo), "v"(hi));
  return r;
}
// async global->LDS DMA, 16B per lane; LDS dest = base + lane*16
static __device__ __forceinline__ void lds_dma16(const void* g, void* l) {
  __builtin_amdgcn_global_load_lds((const __attribute__((address_space(1))) unsigned*)g,
                                   (__attribute__((address_space(3))) unsigned*)l, 16, 0, 0);
}
// gfx950 cross-lane: A'=[A0,B0,A2,B2], B'=[A1,B1,A3,B3] (16-lane rows)
static __device__ __forceinline__ void pl16swap(unsigned& a, unsigned& b) {
  asm("v_permlane16_swap_b32 %0, %1" : "+v"(a), "+v"(b));
}
// raw v_exp_f32 (D = 2^S0): args bounded |x|<~15 here, so ocml's range/denorm
// fixup (~4-6 VALU per call) is dead weight on the busiest pipe.
static __device__ __forceinline__ float exp2_raw(float x) {
  float r;
  asm("v_exp_f32 %0, %1" : "=v"(r) : "v"(x));
  return r;
}

// ---------------- fused prep: x/wq/wp transposes + bias table, one launch ----------------
// blocks [0,3072): x transpose; [3072,3504): qkv_w; [3504,3648): proj_w; [3648,3773): bias
__global__ __launch_bounds__(256) void k_prep(
    const float* __restrict__ x, const float* __restrict__ qkv_w,
    const float* __restrict__ proj_w,
    const float* __restrict__ w1, const float* __restrict__ b1,
    const float* __restrict__ w2, const float* __restrict__ b2,
    __hip_bfloat16* __restrict__ xt, __hip_bfloat16* __restrict__ wtq,
    __hip_bfloat16* __restrict__ wtp, float* __restrict__ tab) {
  const int bid = blockIdx.x;
  const int tid = threadIdx.x;
  if (bid >= 3648) {  // ---- bias table ----
    int g = (bid - 3648) * 256 + tid;
    int p = g >> 3, jc = g & 7;
    if (p >= 63 * 63) return;
    float rh = (float)(p / 63 - 31) * (1.0f / 31.0f);
    float rw = (float)(p % 63 - 31) * (1.0f / 31.0f);
    float acc[8] = {0.f, 0.f, 0.f, 0.f, 0.f, 0.f, 0.f, 0.f};
    const int j0 = jc * 24;
#pragma unroll 4
    for (int j = j0; j < j0 + 24; j++) {
      float pre = fmaf(rh, w1[j], fmaf(rw, w1[HIDDEN + j], b1[j]));
      float gl = 0.5f * pre * (1.0f + erff(pre * 0.70710678118654752f));
#pragma unroll
      for (int h = 0; h < 8; h++) acc[h] = fmaf(gl, w2[j * 8 + h], acc[h]);
    }
#pragma unroll
    for (int msk = 1; msk <= 4; msk <<= 1)
#pragma unroll
      for (int h = 0; h < 8; h++) acc[h] += __shfl_xor(acc[h], msk);
    if (jc == 0) {
#pragma unroll
      for (int h = 0; h < 8; h++)
        tab[h * 3969 + p] = (acc[h] + b2[h]) * 1.4426950408889634f;
    }
    return;
  }
  // ---- transposes ----
  const float* src;
  __hip_bfloat16* dst;
  int R, C, r0, c0;
  if (bid < 3072) {
    int zi = bid / 384, rem = bid % 384;
    R = 384; C = 1024;
    r0 = (rem / 32) * 32; c0 = (rem % 32) * 32;
    src = x + (size_t)zi * R * C;
    dst = xt + (size_t)zi * R * C;
  } else if (bid < 3504) {
    int i = bid - 3072;
    R = 384; C = 1152;
    r0 = (i / 36) * 32; c0 = (i % 36) * 32;
    src = qkv_w; dst = wtq;
  } else {
    int i = bid - 3504;
    R = 384; C = 384;
    r0 = (i / 12) * 32; c0 = (i % 12) * 32;
    src = proj_w; dst = wtp;
  }
  __shared__ float t[32][33];
#pragma unroll
  for (int e = 0; e < 4; e++) {
    int i = tid + e * 256;
    int r = i >> 5, c = i & 31;
    t[r][c] = src[(size_t)(r0 + r) * C + c0 + c];
  }
  __syncthreads();
#pragma unroll
  for (int e = 0; e < 4; e++) {
    int i = tid + e * 256;
    int c = i >> 5, r = i & 31;
    dst[(size_t)(c0 + c) * R + r0 + r] = __float2bfloat16(t[r][c]);
  }
}

// ---------------- QKV GEMM (bf16 MFMA), swizzled DMA staging ----------------
__global__ __launch_bounds__(256) void k_qkv_mfma(
    const __hip_bfloat16* __restrict__ xt,   // [8192][384]
    const __hip_bfloat16* __restrict__ wtq,  // [1152][384]
    const float* __restrict__ qkv_b,
    __hip_bfloat16* __restrict__ Qb,  // [64][1024][64], d-pad zeroed here
    __hip_bfloat16* __restrict__ Kb,  // [64][1024][64], d-pad zeroed here
    __hip_bfloat16* __restrict__ Vt)  // [64][48][1024]
{
  __shared__ __align__(16) char smem[17408];
  short* As = (short*)smem;           // 64x64 shorts, swizzled
  short* Bs = (short*)(smem + 8192);  // 64x64 shorts, swizzled
  float* Vf = (float*)smem;           // 64x68 f32 reuse
  const int n0 = blockIdx.x * 64;  // out-channel tile (fastest: 18 blocks share x-tile)
  const int m0 = blockIdx.y * 64;  // token tile
  const int tid = threadIdx.x;
  const int wv = tid >> 6, lane = tid & 63, quad = lane >> 4, lq = lane & 15;
  const int lrow = lane >> 3;
  const int gsw = ((lane & 7) ^ lrow) * 8;
  const int sw0 = (quad ^ (lq & 7)) * 8;
  const int sw1 = sw0 ^ 32;
  f32x4 acc[4];
#pragma unroll
  for (int nt = 0; nt < 4; nt++) acc[nt] = (f32x4){0.f, 0.f, 0.f, 0.f};
  for (int kk = 0; kk < CC; kk += 64) {
    __syncthreads();
    for (int c = wv; c < 16; c += 4) {
      if (c < 8)
        lds_dma16((const short*)xt + (size_t)(m0 + c * 8 + lrow) * 384 + kk + gsw,
                  smem + c * 1024);
      else
        lds_dma16((const short*)wtq + (size_t)(n0 + (c - 8) * 8 + lrow) * 384 + kk + gsw,
                  smem + 8192 + (c - 8) * 1024);
    }
    __syncthreads();
    short8 a0 = *(const short8*)(As + (wv * 16 + lq) * 64 + sw0);
    short8 a1 = *(const short8*)(As + (wv * 16 + lq) * 64 + sw1);
#pragma unroll
    for (int nt = 0; nt < 4; nt++) {
      acc[nt] = __builtin_amdgcn_mfma_f32_16x16x32_bf16(
          a0, *(const short8*)(Bs + (nt * 16 + lq) * 64 + sw0), acc[nt], 0, 0, 0);
      acc[nt] = __builtin_amdgcn_mfma_f32_16x16x32_bf16(
          a1, *(const short8*)(Bs + (nt * 16 + lq) * 64 + sw1), acc[nt], 0, 0, 0);
    }
  }
  __syncthreads();
  const float qscale = 0.14433756729740643f * 1.4426950408889634f;  // 48^-.5 * log2e
  const float sc = (n0 < 384) ? qscale : 1.0f;
#pragma unroll
  for (int nt = 0; nt < 4; nt++) {
    float bias = qkv_b[n0 + nt * 16 + lq];
#pragma unroll
    for (int r = 0; r < 4; r++)
      Vf[(nt * 16 + lq) * 68 + wv * 16 + quad * 4 + r] = (acc[nt][r] + bias) * sc;
  }
  __syncthreads();
  if (n0 >= 768) {
    // ---- V: transposed write [bh][d][n], 32B/thread ----
    int ch = tid & 63, grp = tid >> 6;
    int cg = n0 - 768 + ch;
    int head = cg / 48, d = cg - head * 48;
    int b = m0 >> 10;
    int n = (m0 & 1023) + grp * 16;
    const float* src = Vf + ch * 68 + grp * 16;
    short o16[16];
#pragma unroll
    for (int k = 0; k < 16; k++) o16[k] = bf16bits(src[k]);
    short* dst = (short*)Vt + ((size_t)(b * 8 + head) * 48 + d) * 1024 + n;
    *(short8*)dst = *(short8*)o16;
    *(short8*)(dst + 8) = *(short8*)(o16 + 8);
  } else {
    // ---- Q or K: row-major [bh][n][d], 32B/thread + d-pad zeros ----
    const int which = n0 >= 384;
    short* Out = which ? (short*)Kb : (short*)Qb;
    int n_l = tid & 63, seg = tid >> 6;
    int rr0 = (n0 - which * 384) + seg * 16;  // 16-aligned; 48=3*16 -> no head split
    int head = rr0 / 48, d0 = rr0 - head * 48;
    int b = m0 >> 10;
    int n_g = (m0 & 1023) + n_l;
    const float* src = Vf + (seg * 16) * 68 + n_l;
    short o16[16];
#pragma unroll
    for (int k = 0; k < 16; k++) o16[k] = bf16bits(src[k * 68]);
    short* dst = Out + (((size_t)(b * 8 + head) << 10) + n_g) * 64 + d0;
    *(short8*)dst = *(short8*)o16;
    *(short8*)(dst + 8) = *(short8*)(o16 + 8);
    if (d0 == 0) {
      short8 z = (short8){0, 0, 0, 0, 0, 0, 0, 0};
      *(short8*)(dst + 48) = z;
      *(short8*)(dst + 56) = z;
    }
  }
}

// ---------------- fused flash attention (R11: 4 waves x 32 q-rows) ----------------
// K/V fragments have no wv-dependence -> reading them once per wave and feeding
// TWO q-row groups (A: wv*32+lq, B: +16) halves LDS b128 reads per unit work and
// doubles per-wave MFMA ILP. Both groups share rloc = wv+1 (tbaseB = tbaseA+16).
// R9 raw exp + R10 cvt_pk/pointer-DMA retained. 256 thr, grid (64,8), 2 blocks/CU.
#define K0_OFF 0       // K dbuf: 2 x 8192
#define V0_OFF 16384   // V dbuf: 2 x 6144
#define TR_OFF 28672   // tab strips: 2 x 2048
#define SMEM_SZ 32768
__global__ __launch_bounds__(256, 2) void k_flash(
    const __hip_bfloat16* __restrict__ Qb, const __hip_bfloat16* __restrict__ Kb,
    const __hip_bfloat16* __restrict__ Vt, const float* __restrict__ tab,
    __hip_bfloat16* __restrict__ ATb)  // [8][1024][384]
{
  __shared__ __align__(16) char smem[SMEM_SZ];
  float* Os = (float*)smem;

  const int tid = threadIdx.x;
  const int wv = tid >> 6, lane = tid & 63, quad = lane >> 4, lq = lane & 15;
  const int bh = blockIdx.x;
  const int q0 = blockIdx.y * 128;
  const int b = bh >> 3, h = bh & 7;
  const int inr0 = q0 >> 5;

  const int nrowA = q0 + wv * 32 + lq;  // group A; group B = +16
  // rloc = wv+1 for both groups (lq<16 keeps both in the same / adjacent 32-group)
  const int tbaseA = (wv + 1) * 63 + lq + 31 - 4 * quad;  // max 298 < 512
  const int tbaseB = tbaseA + 16;

  short8 qfA0, qfA1, qfB0, qfB1;
  {
    const short* qp = (const short*)Qb + ((size_t)(bh << 10) + nrowA) * 64;
    qfA0 = *(const short8*)(qp + quad * 8);
    qfA1 = *(const short8*)(qp + 32 + quad * 8);
    qfB0 = *(const short8*)(qp + 1024 + quad * 8);
    qfB1 = *(const short8*)(qp + 1024 + 32 + quad * 8);
  }
  short8 onesv;
#pragma unroll
  for (int j = 0; j < 8; j++) onesv[j] = (short)0x3F80;  // bf16(1.0)

  f32x4 OA[4], OB[4];  // [3] = L accumulators
#pragma unroll
  for (int dt = 0; dt < 4; dt++) {
    OA[dt] = (f32x4){0.f, 0.f, 0.f, 0.f};
    OB[dt] = (f32x4){0.f, 0.f, 0.f, 0.f};
  }

  const short* kgp = (const short*)Kb + ((size_t)(bh << 10)) * 64;
  const short* vgp = (const short*)Vt + (size_t)bh * 48 * 1024;
  const float* tabg = tab + h * 3969;
  const int lrow = lane >> 3;
  const int gsw = ((lane & 7) ^ lrow) * 8;
  const int sw0 = (quad ^ (lq & 7)) * 8;
  const int sw1 = sw0 ^ 32;
  // V-read swizzle carries the permlane key-permutation (quad -> vq)
  const int vq = ((quad & 1) << 1) | (quad >> 1);
  const int swv0 = (vq ^ (lq & 7)) * 8;
  const int swv1 = swv0 ^ 32;

  // per-wave DMA units (16 total over 4 waves): wave w owns units {w, w+4, w+8, w+12}
  //   units 0-7: K (stride +8192 B/tile), 8-13: V (+128), 14-15: tab (-504)
  const char* kAsrc = (const char*)kgp + (((size_t)(wv * 8 + lrow) * 64 + gsw) << 1);
  const char* kBsrc = (const char*)kgp + (((size_t)((wv + 4) * 8 + lrow) * 64 + gsw) << 1);
  const int kAd = K0_OFF + wv * 1024;
  const int kBd = K0_OFF + (wv + 4) * 1024;
  const char* vsrc = (const char*)vgp + (((size_t)(wv * 8 + lrow) * 1024 + gsw) << 1);
  const int vd = V0_OFF + wv * 1024;
  const char* u4src;
  int u4stride, u4d, u4alt;
  if (wv < 2) {  // V units 12,13 -> V rows (wv+4)*8..
    u4src = (const char*)vgp + (((size_t)((wv + 4) * 8 + lrow) * 1024 + gsw) << 1);
    u4stride = 128;
    u4d = V0_OFF + (wv + 4) * 1024;
    u4alt = 6144;
  } else {  // tab units 14,15
    u4src = (const char*)(tabg + (inr0 + 30) * 63 + lane * 4 + (wv == 3 ? 256 : 0));
    u4stride = -504;
    u4d = TR_OFF + (wv == 3 ? 1024 : 0);
    u4alt = 2048;
  }
  // prologue: tile 0 -> buf0 (4 straight-line DMAs per wave)
  lds_dma16(kAsrc, smem + kAd);
  lds_dma16(kBsrc, smem + kBd);
  lds_dma16(vsrc, smem + vd);
  lds_dma16(u4src, smem + u4d);

  for (int it = 0; it < 16; it++) {
    const int buf = it & 1;
    __syncthreads();  // drains tile-it DMA (vmcnt0 + barrier)
    if (it < 15) {    // prefetch tile it+1 into the other buffer
      const int nbuf = buf ^ 1;
      kAsrc += 8192; kBsrc += 8192; vsrc += 128; u4src += u4stride;
      lds_dma16(kAsrc, smem + kAd + nbuf * 8192);
      lds_dma16(kBsrc, smem + kBd + nbuf * 8192);
      lds_dma16(vsrc, smem + vd + nbuf * 6144);
      lds_dma16(u4src, smem + u4d + nbuf * u4alt);
    }
    const short* Kl = (const short*)(smem + K0_OFF + buf * 8192);
    const short* Vl = (const short*)(smem + V0_OFF + buf * 6144);
    const float* Tl = (const float*)(smem + TR_OFF + buf * 2048);

    // S^T = mfma(K-frag, Q-frag), bias strip as acc init; K frags read ONCE, used 2x
    float sA[4][4], sB[4][4];
    __builtin_amdgcn_s_setprio(1);
#pragma unroll
    for (int nt = 0; nt < 4; nt++) {
      short8 kf0 = *(const short8*)(Kl + (nt * 16 + lq) * 64 + sw0);
      short8 kf1 = *(const short8*)(Kl + (nt * 16 + lq) * 64 + sw1);
      const float* tnA = Tl + tbaseA - (nt >= 2 ? 63 : 0) - (nt & 1) * 16;
      f32x4 c;
      c[0] = tnA[0]; c[1] = tnA[-1]; c[2] = tnA[-2]; c[3] = tnA[-3];
      c = __builtin_amdgcn_mfma_f32_16x16x32_bf16(kf0, qfA0, c, 0, 0, 0);
      c = __builtin_amdgcn_mfma_f32_16x16x32_bf16(kf1, qfA1, c, 0, 0, 0);
#pragma unroll
      for (int r = 0; r < 4; r++) sA[nt][r] = c[r];
      const float* tnB = tnA + 16;
      f32x4 d;
      d[0] = tnB[0]; d[1] = tnB[-1]; d[2] = tnB[-2]; d[3] = tnB[-3];
      d = __builtin_amdgcn_mfma_f32_16x16x32_bf16(kf0, qfB0, d, 0, 0, 0);
      d = __builtin_amdgcn_mfma_f32_16x16x32_bf16(kf1, qfB1, d, 0, 0, 0);
#pragma unroll
      for (int r = 0; r < 4; r++) sB[nt][r] = d[r];
    }
    __builtin_amdgcn_s_setprio(0);
    // no-max softmax: raw v_exp_f32 (shift-invariant; args bounded ~|15|)
#pragma unroll
    for (int nt = 0; nt < 4; nt++)
#pragma unroll
      for (int r = 0; r < 4; r++) {
        sA[nt][r] = exp2_raw(sA[nt][r]);
        sB[nt][r] = exp2_raw(sB[nt][r]);
      }
    // P^T -> bf16 fragments fully in-register (cvt_pk + permlane16_swap), x2 groups
    uint4v pA0, pA1, pB0, pB1;
    {
      unsigned a, bb_;
      a = cvtpk(sA[0][0], sA[0][1]); bb_ = cvtpk(sA[1][0], sA[1][1]);
      pl16swap(a, bb_); pA0[0] = a; pA0[2] = bb_;
      a = cvtpk(sA[0][2], sA[0][3]); bb_ = cvtpk(sA[1][2], sA[1][3]);
      pl16swap(a, bb_); pA0[1] = a; pA0[3] = bb_;
      a = cvtpk(sA[2][0], sA[2][1]); bb_ = cvtpk(sA[3][0], sA[3][1]);
      pl16swap(a, bb_); pA1[0] = a; pA1[2] = bb_;
      a = cvtpk(sA[2][2], sA[2][3]); bb_ = cvtpk(sA[3][2], sA[3][3]);
      pl16swap(a, bb_); pA1[1] = a; pA1[3] = bb_;
      a = cvtpk(sB[0][0], sB[0][1]); bb_ = cvtpk(sB[1][0], sB[1][1]);
      pl16swap(a, bb_); pB0[0] = a; pB0[2] = bb_;
      a = cvtpk(sB[0][2], sB[0][3]); bb_ = cvtpk(sB[1][2], sB[1][3]);
      pl16swap(a, bb_); pB0[1] = a; pB0[3] = bb_;
      a = cvtpk(sB[2][0], sB[2][1]); bb_ = cvtpk(sB[3][0], sB[3][1]);
      pl16swap(a, bb_); pB1[0] = a; pB1[2] = bb_;
      a = cvtpk(sB[2][2], sB[2][3]); bb_ = cvtpk(sB[3][2], sB[3][3]);
      pl16swap(a, bb_); pB1[1] = a; pB1[3] = bb_;
    }
    short8 pfA0 = *(short8*)&pA0;
    short8 pfA1 = *(short8*)&pA1;
    short8 pfB0 = *(short8*)&pB0;
    short8 pfB1 = *(short8*)&pB1;
    // O^T += mfma(V^T-frag, P^T-frag); V frags read ONCE, used 2x; L via ones
    __builtin_amdgcn_s_setprio(1);
#pragma unroll
    for (int dt = 0; dt < 3; dt++) {
      short8 vf = *(const short8*)(Vl + (dt * 16 + lq) * 64 + swv0);
      OA[dt] = __builtin_amdgcn_mfma_f32_16x16x32_bf16(vf, pfA0, OA[dt], 0, 0, 0);
      OB[dt] = __builtin_amdgcn_mfma_f32_16x16x32_bf16(vf, pfB0, OB[dt], 0, 0, 0);
    }
    OA[3] = __builtin_amdgcn_mfma_f32_16x16x32_bf16(onesv, pfA0, OA[3], 0, 0, 0);
    OB[3] = __builtin_amdgcn_mfma_f32_16x16x32_bf16(onesv, pfB0, OB[3], 0, 0, 0);
#pragma unroll
    for (int dt = 0; dt < 3; dt++) {
      short8 vf = *(const short8*)(Vl + (dt * 16 + lq) * 64 + swv1);
      OA[dt] = __builtin_amdgcn_mfma_f32_16x16x32_bf16(vf, pfA1, OA[dt], 0, 0, 0);
      OB[dt] = __builtin_amdgcn_mfma_f32_16x16x32_bf16(vf, pfB1, OB[dt], 0, 0, 0);
    }
    OA[3] = __builtin_amdgcn_mfma_f32_16x16x32_bf16(onesv, pfA1, OA[3], 0, 0, 0);
    OB[3] = __builtin_amdgcn_mfma_f32_16x16x32_bf16(onesv, pfB1, OB[3], 0, 0, 0);
    __builtin_amdgcn_s_setprio(0);
  }
  float invA = 1.0f / OA[3][0];
  float invB = 1.0f / OB[3][0];
  __syncthreads();  // all PV reads done before Os aliases buffers
#pragma unroll
  for (int dt = 0; dt < 3; dt++)
#pragma unroll
    for (int r = 0; r < 4; r++) {
      Os[(wv * 32 + lq) * 52 + dt * 16 + quad * 4 + r] = OA[dt][r] * invA;
      Os[(wv * 32 + 16 + lq) * 52 + dt * 16 + quad * 4 + r] = OB[dt][r] * invB;
    }
  __syncthreads();
  {
    int row = tid >> 1, cg = (tid & 1) * 24;  // 256 thr -> 128 rows x 24 floats
    const float* src = Os + row * 52 + cg;
    short outp[24];
#pragma unroll
    for (int k = 0; k < 24; k++) outp[k] = bf16bits(src[k]);
    short* dst = (short*)ATb + ((size_t)(b << 10) + q0 + row) * 384 + h * 48 + cg;
#pragma unroll
    for (int g = 0; g < 6; g++) *(short4v*)(dst + g * 4) = *(short4v*)(outp + g * 4);
  }
}

// ---------------- proj GEMM (bf16 MFMA), swizzled DMA staging ----------------
__global__ __launch_bounds__(256) void k_proj_mfma(
    const __hip_bfloat16* __restrict__ ATb,  // [8][1024][384]
    const __hip_bfloat16* __restrict__ wtp,  // [384][384] ([cout][cin])
    const float* __restrict__ pb, float* __restrict__ out) {
  __shared__ __align__(16) char smem[16384];
  short* As = (short*)smem;
  short* Bs = (short*)(smem + 8192);
  const int c0 = blockIdx.x * 64;
  const int n0 = blockIdx.y * 64;
  const int b = blockIdx.z;
  const int tid = threadIdx.x;
  const int wv = tid >> 6, lane = tid & 63, quad = lane >> 4, lq = lane & 15;
  const int lrow = lane >> 3;
  const int gsw = ((lane & 7) ^ lrow) * 8;
  const int sw0 = (quad ^ (lq & 7)) * 8;
  const int sw1 = sw0 ^ 32;
  f32x4 acc[4];
#pragma unroll
  for (int nt = 0; nt < 4; nt++) acc[nt] = (f32x4){0.f, 0.f, 0.f, 0.f};
  for (int kk = 0; kk < CC; kk += 64) {
    __syncthreads();
    for (int c = wv; c < 16; c += 4) {
      if (c < 8)
        lds_dma16((const short*)wtp + (size_t)(c0 + c * 8 + lrow) * 384 + kk + gsw,
                  smem + c * 1024);
      else
        lds_dma16((const short*)ATb + ((size_t)(b << 10) + n0 + (c - 8) * 8 + lrow) * 384 + kk + gsw,
                  smem + 8192 + (c - 8) * 1024);
    }
    __syncthreads();
    short8 a0 = *(const short8*)(As + (wv * 16 + lq) * 64 + sw0);
    short8 a1 = *(const short8*)(As + (wv * 16 + lq) * 64 + sw1);
#pragma unroll
    for (int nt = 0; nt < 4; nt++) {
      acc[nt] = __builtin_amdgcn_mfma_f32_16x16x32_bf16(
          a0, *(const short8*)(Bs + (nt * 16 + lq) * 64 + sw0), acc[nt], 0, 0, 0);
      acc[nt] = __builtin_amdgcn_mfma_f32_16x16x32_bf16(
          a1, *(const short8*)(Bs + (nt * 16 + lq) * 64 + sw1), acc[nt], 0, 0, 0);
    }
  }
#pragma unroll
  for (int nt = 0; nt < 4; nt++) {
    int n = n0 + nt * 16 + lq;
#pragma unroll
    for (int r = 0; r < 4; r++) {
      int c = c0 + wv * 16 + quad * 4 + r;
      out[((size_t)b * 384 + c) * 1024 + n] = acc[nt][r] + pb[c];
    }
  }
}

extern "C" void kernel_launch(void* const* d_in, const int* in_sizes, int n_in,
                              void* d_out, int out_size, void* d_ws, size_t ws_size,
                              hipStream_t stream) {
  const float* x = (const float*)d_in[0];
  const float* qkv_w = (const float*)d_in[1];
  const float* qkv_b = (const float*)d_in[2];
  const float* proj_w = (const float*)d_in[3];
  const float* proj_b = (const float*)d_in[4];
  const float* w1 = (const float*)d_in[5];
  const float* b1 = (const float*)d_in[6];
  const float* w2 = (const float*)d_in[7];
  const float* b2 = (const float*)d_in[8];
  float* out = (float*)d_out;

  char* w = (char*)d_ws;
  __hip_bfloat16* xt = (__hip_bfloat16*)w;   w += (size_t)8192 * 384 * 2;
  __hip_bfloat16* wtq = (__hip_bfloat16*)w;  w += (size_t)1152 * 384 * 2;
  __hip_bfloat16* wtp = (__hip_bfloat16*)w;  w += (size_t)384 * 384 * 2;
  __hip_bfloat16* Qb = (__hip_bfloat16*)w;   w += (size_t)64 * 1024 * 64 * 2;
  __hip_bfloat16* Kb = (__hip_bfloat16*)w;   w += (size_t)64 * 1024 * 64 * 2;
  __hip_bfloat16* Vt = (__hip_bfloat16*)w;   w += (size_t)64 * 48 * 1024 * 2;
  __hip_bfloat16* ATb = (__hip_bfloat16*)w;  w += (size_t)8192 * 384 * 2;
  float* tab = (float*)w;                    w += (size_t)8 * 3969 * 4 + 1024;  // +1KB DMA slack

  k_prep<<<dim3(3773), dim3(256), 0, stream>>>(x, qkv_w, proj_w, w1, b1, w2, b2,
                                               xt, wtq, wtp, tab);
  k_qkv_mfma<<<dim3(18, 128), dim3(256), 0, stream>>>(xt, wtq, qkv_b, Qb, Kb, Vt);
  k_flash<<<dim3(64, 8), dim3(256), 0, stream>>>(Qb, Kb, Vt, tab, ATb);
  k_proj_mfma<<<dim3(6, 16, 8), dim3(256), 0, stream>>>(ATb, wtp, proj_b, out);
}

// Round 12
// 134.779 us; speedup vs baseline: 1.2955x; 1.1205x over previous
//
#include <hip/hip_runtime.h>
#include <hip/hip_bf16.h>
#include <math.h>

#define BB 8
#define CC 384
#define NT 1024
#define NHEAD 8
#define HD 48
#define HIDDEN 192
#define THREEC 1152

typedef short short8 __attribute__((ext_vector_type(8)));
typedef short short4v __attribute__((ext_vector_type(4)));
typedef float f32x4 __attribute__((ext_vector_type(4)));
typedef unsigned int uint2v __attribute__((ext_vector_type(2)));
typedef unsigned int uint4v __attribute__((ext_vector_type(4)));

static __device__ __forceinline__ short bf16bits(float v) {
  __hip_bfloat16 h = __float2bfloat16(v);
  return *(short*)&h;
}
// HW pack: low16 = bf16(lo), high16 = bf16(hi), single VALU instr (RNE)
static __device__ __forceinline__ unsigned cvtpk(float lo, float hi) {
  unsigned r;
  asm("v_cvt_pk_bf16_f32 %0, %1, %2" : "=v"(r) : "v"(lo), "v"(hi));
  return r;
}
// async global->LDS DMA, 16B per lane; LDS dest = base + lane*16
static __device__ __forceinline__ void lds_dma16(const void* g, void* l) {
  __builtin_amdgcn_global_load_lds((const __attribute__((address_space(1))) unsigned*)g,
                                   (__attribute__((address_space(3))) unsigned*)l, 16, 0, 0);
}
// gfx950 cross-lane: A'=[A0,B0,A2,B2], B'=[A1,B1,A3,B3] (16-lane rows)
static __device__ __forceinline__ void pl16swap(unsigned& a, unsigned& b) {
  asm("v_permlane16_swap_b32 %0, %1" : "+v"(a), "+v"(b));
}
// raw v_exp_f32 (D = 2^S0): args bounded |x|<~15 here, so ocml's range/denorm
// fixup (~4-6 VALU per call) is dead weight on the busiest pipe.
static __device__ __forceinline__ float exp2_raw(float x) {
  float r;
  asm("v_exp_f32 %0, %1" : "=v"(r) : "v"(x));
  return r;
}

// ---------------- fused prep: bias table FIRST, then x/wq/wp transposes ----------------
// R12: bias blocks lead the grid (they're the long pole -> overlap the cheap
// transposes), split widened 8->32 chunks (497 blocks, ~2/CU), and w1/b1/w2
// staged in LDS so the j-loop reads 6-cycle LDS instead of exposed L1 latency.
// blocks [0,497): bias; [497,3569): x transpose; [3569,4001): qkv_w; [4001,4145): proj_w
#define NB_BIAS 497
__global__ __launch_bounds__(256) void k_prep(
    const float* __restrict__ x, const float* __restrict__ qkv_w,
    const float* __restrict__ proj_w,
    const float* __restrict__ w1, const float* __restrict__ b1,
    const float* __restrict__ w2, const float* __restrict__ b2,
    __hip_bfloat16* __restrict__ xt, __hip_bfloat16* __restrict__ wtq,
    __hip_bfloat16* __restrict__ wtp, float* __restrict__ tab) {
  const int bid = blockIdx.x;
  const int tid = threadIdx.x;
  if (bid < NB_BIAS) {  // ---- bias table ----
    __shared__ float lw[2112];  // w1(384) | b1(192) | w2(1536)
    for (int i = tid; i < 2112; i += 256) {
      float v;
      if (i < 384) v = w1[i];
      else if (i < 576) v = b1[i - 384];
      else v = w2[i - 576];
      lw[i] = v;
    }
    __syncthreads();
    const float* lw1 = lw;        // [2][192]
    const float* lb1 = lw + 384;  // [192]
    const float* lw2 = lw + 576;  // [192][8]
    int g = bid * 256 + tid;
    int p = g >> 5, jc = g & 31;
    if (p >= 63 * 63) return;
    float rh = (float)(p / 63 - 31) * (1.0f / 31.0f);
    float rw = (float)(p % 63 - 31) * (1.0f / 31.0f);
    float acc[8] = {0.f, 0.f, 0.f, 0.f, 0.f, 0.f, 0.f, 0.f};
    const int j0 = jc * 6;
#pragma unroll
    for (int j = j0; j < j0 + 6; j++) {
      float pre = fmaf(rh, lw1[j], fmaf(rw, lw1[HIDDEN + j], lb1[j]));
      float gl = 0.5f * pre * (1.0f + erff(pre * 0.70710678118654752f));
#pragma unroll
      for (int h = 0; h < 8; h++) acc[h] = fmaf(gl, lw2[j * 8 + h], acc[h]);
    }
#pragma unroll
    for (int msk = 1; msk <= 16; msk <<= 1)
#pragma unroll
      for (int h = 0; h < 8; h++) acc[h] += __shfl_xor(acc[h], msk);
    if (jc == 0) {
#pragma unroll
      for (int h = 0; h < 8; h++)
        tab[h * 3969 + p] = (acc[h] + b2[h]) * 1.4426950408889634f;
    }
    return;
  }
  // ---- transposes ----
  const int tb = bid - NB_BIAS;
  const float* src;
  __hip_bfloat16* dst;
  int R, C, r0, c0;
  if (tb < 3072) {
    int zi = tb / 384, rem = tb % 384;
    R = 384; C = 1024;
    r0 = (rem / 32) * 32; c0 = (rem % 32) * 32;
    src = x + (size_t)zi * R * C;
    dst = xt + (size_t)zi * R * C;
  } else if (tb < 3504) {
    int i = tb - 3072;
    R = 384; C = 1152;
    r0 = (i / 36) * 32; c0 = (i % 36) * 32;
    src = qkv_w; dst = wtq;
  } else {
    int i = tb - 3504;
    R = 384; C = 384;
    r0 = (i / 12) * 32; c0 = (i % 12) * 32;
    src = proj_w; dst = wtp;
  }
  __shared__ float t[32][33];
#pragma unroll
  for (int e = 0; e < 4; e++) {
    int i = tid + e * 256;
    int r = i >> 5, c = i & 31;
    t[r][c] = src[(size_t)(r0 + r) * C + c0 + c];
  }
  __syncthreads();
#pragma unroll
  for (int e = 0; e < 4; e++) {
    int i = tid + e * 256;
    int c = i >> 5, r = i & 31;
    dst[(size_t)(c0 + c) * R + r0 + r] = __float2bfloat16(t[r][c]);
  }
}

// ---------------- QKV GEMM (bf16 MFMA), swizzled DMA staging ----------------
__global__ __launch_bounds__(256) void k_qkv_mfma(
    const __hip_bfloat16* __restrict__ xt,   // [8192][384]
    const __hip_bfloat16* __restrict__ wtq,  // [1152][384]
    const float* __restrict__ qkv_b,
    __hip_bfloat16* __restrict__ Qb,  // [64][1024][64], d-pad zeroed here
    __hip_bfloat16* __restrict__ Kb,  // [64][1024][64], d-pad zeroed here
    __hip_bfloat16* __restrict__ Vt)  // [64][48][1024]
{
  __shared__ __align__(16) char smem[17408];
  short* As = (short*)smem;           // 64x64 shorts, swizzled
  short* Bs = (short*)(smem + 8192);  // 64x64 shorts, swizzled
  float* Vf = (float*)smem;           // 64x68 f32 reuse
  const int n0 = blockIdx.x * 64;  // out-channel tile (fastest: 18 blocks share x-tile)
  const int m0 = blockIdx.y * 64;  // token tile
  const int tid = threadIdx.x;
  const int wv = tid >> 6, lane = tid & 63, quad = lane >> 4, lq = lane & 15;
  const int lrow = lane >> 3;
  const int gsw = ((lane & 7) ^ lrow) * 8;
  const int sw0 = (quad ^ (lq & 7)) * 8;
  const int sw1 = sw0 ^ 32;
  f32x4 acc[4];
#pragma unroll
  for (int nt = 0; nt < 4; nt++) acc[nt] = (f32x4){0.f, 0.f, 0.f, 0.f};
  for (int kk = 0; kk < CC; kk += 64) {
    __syncthreads();
    for (int c = wv; c < 16; c += 4) {
      if (c < 8)
        lds_dma16((const short*)xt + (size_t)(m0 + c * 8 + lrow) * 384 + kk + gsw,
                  smem + c * 1024);
      else
        lds_dma16((const short*)wtq + (size_t)(n0 + (c - 8) * 8 + lrow) * 384 + kk + gsw,
                  smem + 8192 + (c - 8) * 1024);
    }
    __syncthreads();
    short8 a0 = *(const short8*)(As + (wv * 16 + lq) * 64 + sw0);
    short8 a1 = *(const short8*)(As + (wv * 16 + lq) * 64 + sw1);
#pragma unroll
    for (int nt = 0; nt < 4; nt++) {
      acc[nt] = __builtin_amdgcn_mfma_f32_16x16x32_bf16(
          a0, *(const short8*)(Bs + (nt * 16 + lq) * 64 + sw0), acc[nt], 0, 0, 0);
      acc[nt] = __builtin_amdgcn_mfma_f32_16x16x32_bf16(
          a1, *(const short8*)(Bs + (nt * 16 + lq) * 64 + sw1), acc[nt], 0, 0, 0);
    }
  }
  __syncthreads();
  const float qscale = 0.14433756729740643f * 1.4426950408889634f;  // 48^-.5 * log2e
  const float sc = (n0 < 384) ? qscale : 1.0f;
#pragma unroll
  for (int nt = 0; nt < 4; nt++) {
    float bias = qkv_b[n0 + nt * 16 + lq];
#pragma unroll
    for (int r = 0; r < 4; r++)
      Vf[(nt * 16 + lq) * 68 + wv * 16 + quad * 4 + r] = (acc[nt][r] + bias) * sc;
  }
  __syncthreads();
  if (n0 >= 768) {
    // ---- V: transposed write [bh][d][n], 32B/thread ----
    int ch = tid & 63, grp = tid >> 6;
    int cg = n0 - 768 + ch;
    int head = cg / 48, d = cg - head * 48;
    int b = m0 >> 10;
    int n = (m0 & 1023) + grp * 16;
    const float* src = Vf + ch * 68 + grp * 16;
    short o16[16];
#pragma unroll
    for (int k = 0; k < 16; k++) o16[k] = bf16bits(src[k]);
    short* dst = (short*)Vt + ((size_t)(b * 8 + head) * 48 + d) * 1024 + n;
    *(short8*)dst = *(short8*)o16;
    *(short8*)(dst + 8) = *(short8*)(o16 + 8);
  } else {
    // ---- Q or K: row-major [bh][n][d], 32B/thread + d-pad zeros ----
    const int which = n0 >= 384;
    short* Out = which ? (short*)Kb : (short*)Qb;
    int n_l = tid & 63, seg = tid >> 6;
    int rr0 = (n0 - which * 384) + seg * 16;  // 16-aligned; 48=3*16 -> no head split
    int head = rr0 / 48, d0 = rr0 - head * 48;
    int b = m0 >> 10;
    int n_g = (m0 & 1023) + n_l;
    const float* src = Vf + (seg * 16) * 68 + n_l;
    short o16[16];
#pragma unroll
    for (int k = 0; k < 16; k++) o16[k] = bf16bits(src[k * 68]);
    short* dst = Out + (((size_t)(b * 8 + head) << 10) + n_g) * 64 + d0;
    *(short8*)dst = *(short8*)o16;
    *(short8*)(dst + 8) = *(short8*)(o16 + 8);
    if (d0 == 0) {
      short8 z = (short8){0, 0, 0, 0, 0, 0, 0, 0};
      *(short8*)(dst + 48) = z;
      *(short8*)(dst + 56) = z;
    }
  }
}

// ---------------- fused flash attention (R11: 4 waves x 32 q-rows) ----------------
// K/V fragments have no wv-dependence -> reading them once per wave and feeding
// TWO q-row groups (A: wv*32+lq, B: +16) halves LDS b128 reads per unit work and
// doubles per-wave MFMA ILP. Both groups share rloc = wv+1 (tbaseB = tbaseA+16).
// R9 raw exp + R10 cvt_pk/pointer-DMA retained. 256 thr, grid (64,8), 2 blocks/CU.
#define K0_OFF 0       // K dbuf: 2 x 8192
#define V0_OFF 16384   // V dbuf: 2 x 6144
#define TR_OFF 28672   // tab strips: 2 x 2048
#define SMEM_SZ 32768
__global__ __launch_bounds__(256, 2) void k_flash(
    const __hip_bfloat16* __restrict__ Qb, const __hip_bfloat16* __restrict__ Kb,
    const __hip_bfloat16* __restrict__ Vt, const float* __restrict__ tab,
    __hip_bfloat16* __restrict__ ATb)  // [8][1024][384]
{
  __shared__ __align__(16) char smem[SMEM_SZ];
  float* Os = (float*)smem;

  const int tid = threadIdx.x;
  const int wv = tid >> 6, lane = tid & 63, quad = lane >> 4, lq = lane & 15;
  const int bh = blockIdx.x;
  const int q0 = blockIdx.y * 128;
  const int b = bh >> 3, h = bh & 7;
  const int inr0 = q0 >> 5;

  const int nrowA = q0 + wv * 32 + lq;  // group A; group B = +16
  // rloc = wv+1 for both groups (lq<16 keeps both in the same / adjacent 32-group)
  const int tbaseA = (wv + 1) * 63 + lq + 31 - 4 * quad;  // max 298 < 512
  const int tbaseB = tbaseA + 16;

  short8 qfA0, qfA1, qfB0, qfB1;
  {
    const short* qp = (const short*)Qb + ((size_t)(bh << 10) + nrowA) * 64;
    qfA0 = *(const short8*)(qp + quad * 8);
    qfA1 = *(const short8*)(qp + 32 + quad * 8);
    qfB0 = *(const short8*)(qp + 1024 + quad * 8);
    qfB1 = *(const short8*)(qp + 1024 + 32 + quad * 8);
  }
  short8 onesv;
#pragma unroll
  for (int j = 0; j < 8; j++) onesv[j] = (short)0x3F80;  // bf16(1.0)

  f32x4 OA[4], OB[4];  // [3] = L accumulators
#pragma unroll
  for (int dt = 0; dt < 4; dt++) {
    OA[dt] = (f32x4){0.f, 0.f, 0.f, 0.f};
    OB[dt] = (f32x4){0.f, 0.f, 0.f, 0.f};
  }

  const short* kgp = (const short*)Kb + ((size_t)(bh << 10)) * 64;
  const short* vgp = (const short*)Vt + (size_t)bh * 48 * 1024;
  const float* tabg = tab + h * 3969;
  const int lrow = lane >> 3;
  const int gsw = ((lane & 7) ^ lrow) * 8;
  const int sw0 = (quad ^ (lq & 7)) * 8;
  const int sw1 = sw0 ^ 32;
  // V-read swizzle carries the permlane key-permutation (quad -> vq)
  const int vq = ((quad & 1) << 1) | (quad >> 1);
  const int swv0 = (vq ^ (lq & 7)) * 8;
  const int swv1 = swv0 ^ 32;

  // per-wave DMA units (16 total over 4 waves): wave w owns units {w, w+4, w+8, w+12}
  //   units 0-7: K (stride +8192 B/tile), 8-13: V (+128), 14-15: tab (-504)
  const char* kAsrc = (const char*)kgp + (((size_t)(wv * 8 + lrow) * 64 + gsw) << 1);
  const char* kBsrc = (const char*)kgp + (((size_t)((wv + 4) * 8 + lrow) * 64 + gsw) << 1);
  const int kAd = K0_OFF + wv * 1024;
  const int kBd = K0_OFF + (wv + 4) * 1024;
  const char* vsrc = (const char*)vgp + (((size_t)(wv * 8 + lrow) * 1024 + gsw) << 1);
  const int vd = V0_OFF + wv * 1024;
  const char* u4src;
  int u4stride, u4d, u4alt;
  if (wv < 2) {  // V units 12,13 -> V rows (wv+4)*8..
    u4src = (const char*)vgp + (((size_t)((wv + 4) * 8 + lrow) * 1024 + gsw) << 1);
    u4stride = 128;
    u4d = V0_OFF + (wv + 4) * 1024;
    u4alt = 6144;
  } else {  // tab units 14,15
    u4src = (const char*)(tabg + (inr0 + 30) * 63 + lane * 4 + (wv == 3 ? 256 : 0));
    u4stride = -504;
    u4d = TR_OFF + (wv == 3 ? 1024 : 0);
    u4alt = 2048;
  }
  // prologue: tile 0 -> buf0 (4 straight-line DMAs per wave)
  lds_dma16(kAsrc, smem + kAd);
  lds_dma16(kBsrc, smem + kBd);
  lds_dma16(vsrc, smem + vd);
  lds_dma16(u4src, smem + u4d);

  for (int it = 0; it < 16; it++) {
    const int buf = it & 1;
    __syncthreads();  // drains tile-it DMA (vmcnt0 + barrier)
    if (it < 15) {    // prefetch tile it+1 into the other buffer
      const int nbuf = buf ^ 1;
      kAsrc += 8192; kBsrc += 8192; vsrc += 128; u4src += u4stride;
      lds_dma16(kAsrc, smem + kAd + nbuf * 8192);
      lds_dma16(kBsrc, smem + kBd + nbuf * 8192);
      lds_dma16(vsrc, smem + vd + nbuf * 6144);
      lds_dma16(u4src, smem + u4d + nbuf * u4alt);
    }
    const short* Kl = (const short*)(smem + K0_OFF + buf * 8192);
    const short* Vl = (const short*)(smem + V0_OFF + buf * 6144);
    const float* Tl = (const float*)(smem + TR_OFF + buf * 2048);

    // S^T = mfma(K-frag, Q-frag), bias strip as acc init; K frags read ONCE, used 2x
    float sA[4][4], sB[4][4];
    __builtin_amdgcn_s_setprio(1);
#pragma unroll
    for (int nt = 0; nt < 4; nt++) {
      short8 kf0 = *(const short8*)(Kl + (nt * 16 + lq) * 64 + sw0);
      short8 kf1 = *(const short8*)(Kl + (nt * 16 + lq) * 64 + sw1);
      const float* tnA = Tl + tbaseA - (nt >= 2 ? 63 : 0) - (nt & 1) * 16;
      f32x4 c;
      c[0] = tnA[0]; c[1] = tnA[-1]; c[2] = tnA[-2]; c[3] = tnA[-3];
      c = __builtin_amdgcn_mfma_f32_16x16x32_bf16(kf0, qfA0, c, 0, 0, 0);
      c = __builtin_amdgcn_mfma_f32_16x16x32_bf16(kf1, qfA1, c, 0, 0, 0);
#pragma unroll
      for (int r = 0; r < 4; r++) sA[nt][r] = c[r];
      const float* tnB = tnA + 16;
      f32x4 d;
      d[0] = tnB[0]; d[1] = tnB[-1]; d[2] = tnB[-2]; d[3] = tnB[-3];
      d = __builtin_amdgcn_mfma_f32_16x16x32_bf16(kf0, qfB0, d, 0, 0, 0);
      d = __builtin_amdgcn_mfma_f32_16x16x32_bf16(kf1, qfB1, d, 0, 0, 0);
#pragma unroll
      for (int r = 0; r < 4; r++) sB[nt][r] = d[r];
    }
    __builtin_amdgcn_s_setprio(0);
    // no-max softmax: raw v_exp_f32 (shift-invariant; args bounded ~|15|)
#pragma unroll
    for (int nt = 0; nt < 4; nt++)
#pragma unroll
      for (int r = 0; r < 4; r++) {
        sA[nt][r] = exp2_raw(sA[nt][r]);
        sB[nt][r] = exp2_raw(sB[nt][r]);
      }
    // P^T -> bf16 fragments fully in-register (cvt_pk + permlane16_swap), x2 groups
    uint4v pA0, pA1, pB0, pB1;
    {
      unsigned a, bb_;
      a = cvtpk(sA[0][0], sA[0][1]); bb_ = cvtpk(sA[1][0], sA[1][1]);
      pl16swap(a, bb_); pA0[0] = a; pA0[2] = bb_;
      a = cvtpk(sA[0][2], sA[0][3]); bb_ = cvtpk(sA[1][2], sA[1][3]);
      pl16swap(a, bb_); pA0[1] = a; pA0[3] = bb_;
      a = cvtpk(sA[2][0], sA[2][1]); bb_ = cvtpk(sA[3][0], sA[3][1]);
      pl16swap(a, bb_); pA1[0] = a; pA1[2] = bb_;
      a = cvtpk(sA[2][2], sA[2][3]); bb_ = cvtpk(sA[3][2], sA[3][3]);
      pl16swap(a, bb_); pA1[1] = a; pA1[3] = bb_;
      a = cvtpk(sB[0][0], sB[0][1]); bb_ = cvtpk(sB[1][0], sB[1][1]);
      pl16swap(a, bb_); pB0[0] = a; pB0[2] = bb_;
      a = cvtpk(sB[0][2], sB[0][3]); bb_ = cvtpk(sB[1][2], sB[1][3]);
      pl16swap(a, bb_); pB0[1] = a; pB0[3] = bb_;
      a = cvtpk(sB[2][0], sB[2][1]); bb_ = cvtpk(sB[3][0], sB[3][1]);
      pl16swap(a, bb_); pB1[0] = a; pB1[2] = bb_;
      a = cvtpk(sB[2][2], sB[2][3]); bb_ = cvtpk(sB[3][2], sB[3][3]);
      pl16swap(a, bb_); pB1[1] = a; pB1[3] = bb_;
    }
    short8 pfA0 = *(short8*)&pA0;
    short8 pfA1 = *(short8*)&pA1;
    short8 pfB0 = *(short8*)&pB0;
    short8 pfB1 = *(short8*)&pB1;
    // O^T += mfma(V^T-frag, P^T-frag); V frags read ONCE, used 2x; L via ones
    __builtin_amdgcn_s_setprio(1);
#pragma unroll
    for (int dt = 0; dt < 3; dt++) {
      short8 vf = *(const short8*)(Vl + (dt * 16 + lq) * 64 + swv0);
      OA[dt] = __builtin_amdgcn_mfma_f32_16x16x32_bf16(vf, pfA0, OA[dt], 0, 0, 0);
      OB[dt] = __builtin_amdgcn_mfma_f32_16x16x32_bf16(vf, pfB0, OB[dt], 0, 0, 0);
    }
    OA[3] = __builtin_amdgcn_mfma_f32_16x16x32_bf16(onesv, pfA0, OA[3], 0, 0, 0);
    OB[3] = __builtin_amdgcn_mfma_f32_16x16x32_bf16(onesv, pfB0, OB[3], 0, 0, 0);
#pragma unroll
    for (int dt = 0; dt < 3; dt++) {
      short8 vf = *(const short8*)(Vl + (dt * 16 + lq) * 64 + swv1);
      OA[dt] = __builtin_amdgcn_mfma_f32_16x16x32_bf16(vf, pfA1, OA[dt], 0, 0, 0);
      OB[dt] = __builtin_amdgcn_mfma_f32_16x16x32_bf16(vf, pfB1, OB[dt], 0, 0, 0);
    }
    OA[3] = __builtin_amdgcn_mfma_f32_16x16x32_bf16(onesv, pfA1, OA[3], 0, 0, 0);
    OB[3] = __builtin_amdgcn_mfma_f32_16x16x32_bf16(onesv, pfB1, OB[3], 0, 0, 0);
    __builtin_amdgcn_s_setprio(0);
  }
  float invA = 1.0f / OA[3][0];
  float invB = 1.0f / OB[3][0];
  __syncthreads();  // all PV reads done before Os aliases buffers
#pragma unroll
  for (int dt = 0; dt < 3; dt++)
#pragma unroll
    for (int r = 0; r < 4; r++) {
      Os[(wv * 32 + lq) * 52 + dt * 16 + quad * 4 + r] = OA[dt][r] * invA;
      Os[(wv * 32 + 16 + lq) * 52 + dt * 16 + quad * 4 + r] = OB[dt][r] * invB;
    }
  __syncthreads();
  {
    int row = tid >> 1, cg = (tid & 1) * 24;  // 256 thr -> 128 rows x 24 floats
    const float* src = Os + row * 52 + cg;
    short outp[24];
#pragma unroll
    for (int k = 0; k < 24; k++) outp[k] = bf16bits(src[k]);
    short* dst = (short*)ATb + ((size_t)(b << 10) + q0 + row) * 384 + h * 48 + cg;
#pragma unroll
    for (int g = 0; g < 6; g++) *(short4v*)(dst + g * 4) = *(short4v*)(outp + g * 4);
  }
}

// ---------------- proj GEMM (bf16 MFMA), swizzled DMA staging ----------------
__global__ __launch_bounds__(256) void k_proj_mfma(
    const __hip_bfloat16* __restrict__ ATb,  // [8][1024][384]
    const __hip_bfloat16* __restrict__ wtp,  // [384][384] ([cout][cin])
    const float* __restrict__ pb, float* __restrict__ out) {
  __shared__ __align__(16) char smem[16384];
  short* As = (short*)smem;
  short* Bs = (short*)(smem + 8192);
  const int c0 = blockIdx.x * 64;
  const int n0 = blockIdx.y * 64;
  const int b = blockIdx.z;
  const int tid = threadIdx.x;
  const int wv = tid >> 6, lane = tid & 63, quad = lane >> 4, lq = lane & 15;
  const int lrow = lane >> 3;
  const int gsw = ((lane & 7) ^ lrow) * 8;
  const int sw0 = (quad ^ (lq & 7)) * 8;
  const int sw1 = sw0 ^ 32;
  f32x4 acc[4];
#pragma unroll
  for (int nt = 0; nt < 4; nt++) acc[nt] = (f32x4){0.f, 0.f, 0.f, 0.f};
  for (int kk = 0; kk < CC; kk += 64) {
    __syncthreads();
    for (int c = wv; c < 16; c += 4) {
      if (c < 8)
        lds_dma16((const short*)wtp + (size_t)(c0 + c * 8 + lrow) * 384 + kk + gsw,
                  smem + c * 1024);
      else
        lds_dma16((const short*)ATb + ((size_t)(b << 10) + n0 + (c - 8) * 8 + lrow) * 384 + kk + gsw,
                  smem + 8192 + (c - 8) * 1024);
    }
    __syncthreads();
    short8 a0 = *(const short8*)(As + (wv * 16 + lq) * 64 + sw0);
    short8 a1 = *(const short8*)(As + (wv * 16 + lq) * 64 + sw1);
#pragma unroll
    for (int nt = 0; nt < 4; nt++) {
      acc[nt] = __builtin_amdgcn_mfma_f32_16x16x32_bf16(
          a0, *(const short8*)(Bs + (nt * 16 + lq) * 64 + sw0), acc[nt], 0, 0, 0);
      acc[nt] = __builtin_amdgcn_mfma_f32_16x16x32_bf16(
          a1, *(const short8*)(Bs + (nt * 16 + lq) * 64 + sw1), acc[nt], 0, 0, 0);
    }
  }
#pragma unroll
  for (int nt = 0; nt < 4; nt++) {
    int n = n0 + nt * 16 + lq;
#pragma unroll
    for (int r = 0; r < 4; r++) {
      int c = c0 + wv * 16 + quad * 4 + r;
      out[((size_t)b * 384 + c) * 1024 + n] = acc[nt][r] + pb[c];
    }
  }
}

extern "C" void kernel_launch(void* const* d_in, const int* in_sizes, int n_in,
                              void* d_out, int out_size, void* d_ws, size_t ws_size,
                              hipStream_t stream) {
  const float* x = (const float*)d_in[0];
  const float* qkv_w = (const float*)d_in[1];
  const float* qkv_b = (const float*)d_in[2];
  const float* proj_w = (const float*)d_in[3];
  const float* proj_b = (const float*)d_in[4];
  const float* w1 = (const float*)d_in[5];
  const float* b1 = (const float*)d_in[6];
  const float* w2 = (const float*)d_in[7];
  const float* b2 = (const float*)d_in[8];
  float* out = (float*)d_out;

  char* w = (char*)d_ws;
  __hip_bfloat16* xt = (__hip_bfloat16*)w;   w += (size_t)8192 * 384 * 2;
  __hip_bfloat16* wtq = (__hip_bfloat16*)w;  w += (size_t)1152 * 384 * 2;
  __hip_bfloat16* wtp = (__hip_bfloat16*)w;  w += (size_t)384 * 384 * 2;
  __hip_bfloat16* Qb = (__hip_bfloat16*)w;   w += (size_t)64 * 1024 * 64 * 2;
  __hip_bfloat16* Kb = (__hip_bfloat16*)w;   w += (size_t)64 * 1024 * 64 * 2;
  __hip_bfloat16* Vt = (__hip_bfloat16*)w;   w += (size_t)64 * 48 * 1024 * 2;
  __hip_bfloat16* ATb = (__hip_bfloat16*)w;  w += (size_t)8192 * 384 * 2;
  float* tab = (float*)w;                    w += (size_t)8 * 3969 * 4 + 1024;  // +1KB DMA slack

  k_prep<<<dim3(4145), dim3(256), 0, stream>>>(x, qkv_w, proj_w, w1, b1, w2, b2,
                                               xt, wtq, wtp, tab);
  k_qkv_mfma<<<dim3(18, 128), dim3(256), 0, stream>>>(xt, wtq, qkv_b, Qb, Kb, Vt);
  k_flash<<<dim3(64, 8), dim3(256), 0, stream>>>(Qb, Kb, Vt, tab, ATb);
  k_proj_mfma<<<dim3(6, 16, 8), dim3(256), 0, stream>>>(ATb, wtp, proj_b, out);
}